// Round 1
// baseline (5983.761 us; speedup 1.0000x reference)
//
#include <hip/hip_runtime.h>
#include <math.h>

// GATv2Conv forward, f32.
// Inputs: x[50000,128], edge_index[2,800000] (int32), W_l[128,128], W_r[128,128],
//         att[8,16], bias[128].  Output: out[50000,128] f32.
//
// ws layout (floats): x_l[N*128] | x_r[N*128] | denom[N*8]   = 52.8 MB

#define NN 50000
#define NE 800000
#define NHEADS 8
#define CH 16
#define FDIM 128
#define NEG_SLOPE 0.2f

// ---------------- init: out = bias (broadcast), denom = 0 ----------------
__global__ void gat_init_kernel(float* __restrict__ out,
                                float* __restrict__ denom,
                                const float* __restrict__ bias) {
    int idx = blockIdx.x * blockDim.x + threadIdx.x;
    if (idx < NN * FDIM) out[idx] = bias[idx & (FDIM - 1)];
    if (idx < NN * NHEADS) denom[idx] = 0.0f;
}

// ---------------- projections: x_l = x @ W_l^T, x_r = x @ W_r^T ----------
// Block = 256 threads, handles 8 nodes. Thread t computes output column t
// (t<128 -> x_l col t, t>=128 -> x_r col t-128) for all 8 nodes, so each W
// element fetched from cache is reused 8x in registers.
#define NODE_TILE 8
__global__ __launch_bounds__(256) void gat_proj_kernel(
        const float* __restrict__ x,
        const float* __restrict__ Wl,
        const float* __restrict__ Wr,
        float* __restrict__ xl,
        float* __restrict__ xr) {
    __shared__ float xs[NODE_TILE][FDIM];
    const int node0 = blockIdx.x * NODE_TILE;
    const int t = threadIdx.x;

    // cooperative load of 8 x-rows (1024 floats) into LDS
    #pragma unroll
    for (int i = 0; i < NODE_TILE * FDIM / 256; ++i) {
        int e = t + i * 256;
        xs[e >> 7][e & (FDIM - 1)] = x[node0 * FDIM + e];
    }
    __syncthreads();

    const float* W = (t < FDIM) ? (Wl + t * FDIM) : (Wr + (t - FDIM) * FDIM);
    const float4* W4 = reinterpret_cast<const float4*>(W);

    float acc[NODE_TILE];
    #pragma unroll
    for (int i = 0; i < NODE_TILE; ++i) acc[i] = 0.0f;

    #pragma unroll 8
    for (int k4 = 0; k4 < FDIM / 4; ++k4) {
        float4 w = W4[k4];
        #pragma unroll
        for (int i = 0; i < NODE_TILE; ++i) {
            const float4 xv = reinterpret_cast<const float4*>(xs[i])[k4];
            acc[i] += xv.x * w.x + xv.y * w.y + xv.z * w.z + xv.w * w.w;
        }
    }

    float* dstp = (t < FDIM) ? (xl + node0 * FDIM + t)
                             : (xr + node0 * FDIM + (t - FDIM));
    #pragma unroll
    for (int i = 0; i < NODE_TILE; ++i) dstp[i * FDIM] = acc[i];
}

// ------------- per-(edge,head) alpha helper (recomputed in both passes) ----
__device__ __forceinline__ float edge_alpha(const float* __restrict__ xl,
                                            const float* __restrict__ xr,
                                            const float* __restrict__ att,
                                            int src, int dst, int h,
                                            float4* xj_out) {
    const float4* xjp = reinterpret_cast<const float4*>(xl + src * FDIM + h * CH);
    const float4* xip = reinterpret_cast<const float4*>(xr + dst * FDIM + h * CH);
    const float4* ap  = reinterpret_cast<const float4*>(att + h * CH);
    float alpha = 0.0f;
    #pragma unroll
    for (int q = 0; q < CH / 4; ++q) {
        float4 xj = xjp[q];
        float4 xi = xip[q];
        float4 a  = ap[q];
        if (xj_out) xj_out[q] = xj;
        float e0 = xi.x + xj.x; e0 = (e0 > 0.0f) ? e0 : NEG_SLOPE * e0;
        float e1 = xi.y + xj.y; e1 = (e1 > 0.0f) ? e1 : NEG_SLOPE * e1;
        float e2 = xi.z + xj.z; e2 = (e2 > 0.0f) ? e2 : NEG_SLOPE * e2;
        float e3 = xi.w + xj.w; e3 = (e3 > 0.0f) ? e3 : NEG_SLOPE * e3;
        alpha += a.x * e0 + a.y * e1 + a.z * e2 + a.w * e3;
    }
    return alpha;
}

// ---------------- pass 1: denom[dst,h] += exp(alpha) ----------------------
// (No segment-max: alpha has std ~0.4, global max < ~3; exp is safe in f32
//  and the exp(amax) factor cancels exactly in the normalization.)
__global__ __launch_bounds__(256) void gat_denom_kernel(
        const int* __restrict__ ei,
        const float* __restrict__ xl,
        const float* __restrict__ xr,
        const float* __restrict__ att,
        float* __restrict__ denom) {
    int idx = blockIdx.x * blockDim.x + threadIdx.x;
    if (idx >= NE * NHEADS) return;
    int m = idx >> 3;
    int h = idx & 7;
    int src = ei[m];
    int dst = ei[NE + m];
    float alpha = edge_alpha(xl, xr, att, src, dst, h, nullptr);
    float ea = expf(alpha);
    atomicAdd(&denom[dst * NHEADS + h], ea);
}

// ---------------- pass 2: out[dst] += (exp(alpha)/denom) * x_j ------------
__global__ __launch_bounds__(256) void gat_scatter_kernel(
        const int* __restrict__ ei,
        const float* __restrict__ xl,
        const float* __restrict__ xr,
        const float* __restrict__ att,
        const float* __restrict__ denom,
        float* __restrict__ out) {
    int idx = blockIdx.x * blockDim.x + threadIdx.x;
    if (idx >= NE * NHEADS) return;
    int m = idx >> 3;
    int h = idx & 7;
    int src = ei[m];
    int dst = ei[NE + m];
    float4 xj[CH / 4];
    float alpha = edge_alpha(xl, xr, att, src, dst, h, xj);
    float ea = expf(alpha);
    float a = ea / (denom[dst * NHEADS + h] + 1e-16f);
    float* op = out + dst * FDIM + h * CH;
    #pragma unroll
    for (int q = 0; q < CH / 4; ++q) {
        atomicAdd(op + q * 4 + 0, a * xj[q].x);
        atomicAdd(op + q * 4 + 1, a * xj[q].y);
        atomicAdd(op + q * 4 + 2, a * xj[q].z);
        atomicAdd(op + q * 4 + 3, a * xj[q].w);
    }
}

extern "C" void kernel_launch(void* const* d_in, const int* in_sizes, int n_in,
                              void* d_out, int out_size, void* d_ws, size_t ws_size,
                              hipStream_t stream) {
    const float* x    = (const float*)d_in[0];
    const int*   ei   = (const int*)d_in[1];
    const float* Wl   = (const float*)d_in[2];
    const float* Wr   = (const float*)d_in[3];
    const float* att  = (const float*)d_in[4];
    const float* bias = (const float*)d_in[5];
    float* out = (float*)d_out;

    float* ws    = (float*)d_ws;
    float* xl    = ws;                       // NN*FDIM
    float* xr    = ws + (size_t)NN * FDIM;   // NN*FDIM
    float* denom = ws + (size_t)2 * NN * FDIM; // NN*NHEADS

    // init out=bias, denom=0
    {
        int total = NN * FDIM;
        gat_init_kernel<<<(total + 255) / 256, 256, 0, stream>>>(out, denom, bias);
    }
    // projections
    gat_proj_kernel<<<NN / NODE_TILE, 256, 0, stream>>>(x, Wl, Wr, xl, xr);
    // softmax denominator
    {
        int total = NE * NHEADS;
        gat_denom_kernel<<<(total + 255) / 256, 256, 0, stream>>>(ei, xl, xr, att, denom);
    }
    // weighted scatter
    {
        int total = NE * NHEADS;
        gat_scatter_kernel<<<(total + 255) / 256, 256, 0, stream>>>(ei, xl, xr, att, denom, out);
    }
}

// Round 2
// 374.575 us; speedup vs baseline: 15.9748x; 15.9748x over previous
//
#include <hip/hip_runtime.h>
#include <math.h>

// GATv2Conv forward, f32. CSR-based (no f32 output atomics).
// Inputs: x[50000,128], edge_index[2,800000] (int32), W_l[128,128], W_r[128,128],
//         att[8,16], bias[128].  Output: out[50000,128] f32.

#define NN 50000
#define NE 800000
#define NHEADS 8
#define CH 16
#define FDIM 128
#define NEG_SLOPE 0.2f

#define SCAN_BLOCK 256
#define NBLK ((NN + SCAN_BLOCK - 1) / SCAN_BLOCK)   // 196

// ---------------- projections: x_l = x @ W_l^T, x_r = x @ W_r^T ----------
#define NODE_TILE 8
__global__ __launch_bounds__(256) void gat_proj_kernel(
        const float* __restrict__ x,
        const float* __restrict__ Wl,
        const float* __restrict__ Wr,
        float* __restrict__ xl,
        float* __restrict__ xr) {
    __shared__ float xs[NODE_TILE][FDIM];
    const int node0 = blockIdx.x * NODE_TILE;
    const int t = threadIdx.x;

    #pragma unroll
    for (int i = 0; i < NODE_TILE * FDIM / 256; ++i) {
        int e = t + i * 256;
        xs[e >> 7][e & (FDIM - 1)] = x[node0 * FDIM + e];
    }
    __syncthreads();

    const float* W = (t < FDIM) ? (Wl + t * FDIM) : (Wr + (t - FDIM) * FDIM);
    const float4* W4 = reinterpret_cast<const float4*>(W);

    float acc[NODE_TILE];
    #pragma unroll
    for (int i = 0; i < NODE_TILE; ++i) acc[i] = 0.0f;

    #pragma unroll 8
    for (int k4 = 0; k4 < FDIM / 4; ++k4) {
        float4 w = W4[k4];
        #pragma unroll
        for (int i = 0; i < NODE_TILE; ++i) {
            const float4 xv = reinterpret_cast<const float4*>(xs[i])[k4];
            acc[i] += xv.x * w.x + xv.y * w.y + xv.z * w.z + xv.w * w.w;
        }
    }

    float* dstp = (t < FDIM) ? (xl + node0 * FDIM + t)
                             : (xr + node0 * FDIM + (t - FDIM));
    #pragma unroll
    for (int i = 0; i < NODE_TILE; ++i) dstp[i * FDIM] = acc[i];
}

// ---------------- CSR build --------------------------------------------
__global__ void gat_zero_kernel(int* __restrict__ deg) {
    int i = blockIdx.x * blockDim.x + threadIdx.x;
    if (i < NN) deg[i] = 0;
}

__global__ void gat_hist_kernel(const int* __restrict__ ei, int* __restrict__ deg) {
    int m = blockIdx.x * blockDim.x + threadIdx.x;
    if (m < NE) atomicAdd(&deg[ei[NE + m]], 1);
}

__global__ __launch_bounds__(SCAN_BLOCK) void gat_blocksum_kernel(
        const int* __restrict__ deg, int* __restrict__ blocksum) {
    int i = blockIdx.x * SCAN_BLOCK + threadIdx.x;
    int v = (i < NN) ? deg[i] : 0;
    #pragma unroll
    for (int off = 1; off < 64; off <<= 1) v += __shfl_xor(v, off);
    __shared__ int wsum[4];
    if ((threadIdx.x & 63) == 0) wsum[threadIdx.x >> 6] = v;
    __syncthreads();
    if (threadIdx.x == 0)
        blocksum[blockIdx.x] = wsum[0] + wsum[1] + wsum[2] + wsum[3];
}

__global__ __launch_bounds__(SCAN_BLOCK) void gat_scanblk_kernel(
        const int* __restrict__ blocksum, int* __restrict__ blockoff) {
    __shared__ int buf[SCAN_BLOCK];
    int t = threadIdx.x;
    int v = (t < NBLK) ? blocksum[t] : 0;
    buf[t] = v;
    __syncthreads();
    for (int off = 1; off < SCAN_BLOCK; off <<= 1) {
        int add = (t >= off) ? buf[t - off] : 0;
        __syncthreads();
        buf[t] += add;
        __syncthreads();
    }
    if (t < NBLK) blockoff[t] = buf[t] - v;   // exclusive
}

__global__ __launch_bounds__(SCAN_BLOCK) void gat_scanfinal_kernel(
        const int* __restrict__ deg, const int* __restrict__ blockoff,
        int* __restrict__ rowstart, int* __restrict__ cursor) {
    __shared__ int buf[SCAN_BLOCK];
    int t = threadIdx.x;
    int i = blockIdx.x * SCAN_BLOCK + t;
    int v = (i < NN) ? deg[i] : 0;
    buf[t] = v;
    __syncthreads();
    for (int off = 1; off < SCAN_BLOCK; off <<= 1) {
        int add = (t >= off) ? buf[t - off] : 0;
        __syncthreads();
        buf[t] += add;
        __syncthreads();
    }
    int excl = blockoff[blockIdx.x] + buf[t] - v;
    if (i < NN) { rowstart[i] = excl; cursor[i] = excl; }
    if (i == NN - 1) rowstart[NN] = excl + v;
}

__global__ void gat_fillcsr_kernel(const int* __restrict__ ei,
                                   int* __restrict__ cursor,
                                   int* __restrict__ csr_src) {
    int m = blockIdx.x * blockDim.x + threadIdx.x;
    if (m < NE) {
        int dst = ei[NE + m];
        int pos = atomicAdd(&cursor[dst], 1);
        csr_src[pos] = ei[m];
    }
}

// ---------------- fused aggregate: softmax + weighted sum, 1 write/elem ---
// 128 threads per node (2 nodes per 256-block). Thread t = channel, head = t>>4.
// alpha reduced across each 16-lane group via shfl_xor.
__global__ __launch_bounds__(256) void gat_aggregate_kernel(
        const float* __restrict__ xl,
        const float* __restrict__ xr,
        const float* __restrict__ att,
        const float* __restrict__ bias,
        const int* __restrict__ rowstart,
        const int* __restrict__ csr_src,
        float* __restrict__ out) {
    int node = blockIdx.x * 2 + (threadIdx.x >> 7);
    int t = threadIdx.x & 127;
    if (node >= NN) return;

    float xi = xr[node * FDIM + t];
    float at = att[t];
    float bi = bias[t];
    int e0 = rowstart[node];
    int e1 = rowstart[node + 1];

    float acc = 0.0f, den = 0.0f;
    for (int e = e0; e < e1; ++e) {
        int src = csr_src[e];
        float xj = xl[src * FDIM + t];
        float s = xi + xj;
        s = (s > 0.0f) ? s : NEG_SLOPE * s;
        float p = s * at;
        p += __shfl_xor(p, 1);
        p += __shfl_xor(p, 2);
        p += __shfl_xor(p, 4);
        p += __shfl_xor(p, 8);
        float ea = __expf(p);
        acc += ea * xj;
        den += ea;
    }
    out[node * FDIM + t] = acc / (den + 1e-16f) + bi;
}

extern "C" void kernel_launch(void* const* d_in, const int* in_sizes, int n_in,
                              void* d_out, int out_size, void* d_ws, size_t ws_size,
                              hipStream_t stream) {
    const float* x    = (const float*)d_in[0];
    const int*   ei   = (const int*)d_in[1];
    const float* Wl   = (const float*)d_in[2];
    const float* Wr   = (const float*)d_in[3];
    const float* att  = (const float*)d_in[4];
    const float* bias = (const float*)d_in[5];
    float* out = (float*)d_out;

    // ws layout
    float* ws = (float*)d_ws;
    float* xl = ws;                                  // NN*FDIM f32
    float* xr = xl + (size_t)NN * FDIM;              // NN*FDIM f32
    int* ibase      = (int*)(xr + (size_t)NN * FDIM);
    int* deg        = ibase;                         // NN
    int* rowstart   = deg + NN;                      // NN+1
    int* cursor     = rowstart + NN + 1;             // NN
    int* blocksum   = cursor + NN;                   // NBLK (pad 256)
    int* blockoff   = blocksum + 256;                // NBLK (pad 256)
    int* csr_src    = blockoff + 256;                // NE
    // total ≈ 55.0 MB

    gat_zero_kernel<<<(NN + 255) / 256, 256, 0, stream>>>(deg);
    gat_hist_kernel<<<(NE + 255) / 256, 256, 0, stream>>>(ei, deg);
    gat_blocksum_kernel<<<NBLK, SCAN_BLOCK, 0, stream>>>(deg, blocksum);
    gat_scanblk_kernel<<<1, SCAN_BLOCK, 0, stream>>>(blocksum, blockoff);
    gat_scanfinal_kernel<<<NBLK, SCAN_BLOCK, 0, stream>>>(deg, blockoff, rowstart, cursor);
    gat_fillcsr_kernel<<<(NE + 255) / 256, 256, 0, stream>>>(ei, cursor, csr_src);

    gat_proj_kernel<<<NN / NODE_TILE, 256, 0, stream>>>(x, Wl, Wr, xl, xr);

    gat_aggregate_kernel<<<(NN + 1) / 2, 256, 0, stream>>>(
        xl, xr, att, bias, rowstart, csr_src, out);
}

// Round 3
// 255.759 us; speedup vs baseline: 23.3961x; 1.4646x over previous
//
#include <hip/hip_runtime.h>
#include <math.h>

// GATv2Conv forward, f32. CSR-based (no f32 output atomics).
// Aggregate: 32 threads/node (float4 per lane), edge loop unrolled x4 with
// independent accumulator chains for memory-level parallelism.

#define NN 50000
#define NE 800000
#define NHEADS 8
#define CH 16
#define FDIM 128
#define NEG_SLOPE 0.2f

#define SCAN_BLOCK 256
#define NBLK ((NN + SCAN_BLOCK - 1) / SCAN_BLOCK)   // 196

// ---------------- projections: x_l = x @ W_l^T, x_r = x @ W_r^T ----------
#define NODE_TILE 8
__global__ __launch_bounds__(256) void gat_proj_kernel(
        const float* __restrict__ x,
        const float* __restrict__ Wl,
        const float* __restrict__ Wr,
        float* __restrict__ xl,
        float* __restrict__ xr) {
    __shared__ float xs[NODE_TILE][FDIM];
    const int node0 = blockIdx.x * NODE_TILE;
    const int t = threadIdx.x;

    #pragma unroll
    for (int i = 0; i < NODE_TILE * FDIM / 256; ++i) {
        int e = t + i * 256;
        xs[e >> 7][e & (FDIM - 1)] = x[node0 * FDIM + e];
    }
    __syncthreads();

    const float* W = (t < FDIM) ? (Wl + t * FDIM) : (Wr + (t - FDIM) * FDIM);
    const float4* W4 = reinterpret_cast<const float4*>(W);

    float acc[NODE_TILE];
    #pragma unroll
    for (int i = 0; i < NODE_TILE; ++i) acc[i] = 0.0f;

    #pragma unroll 8
    for (int k4 = 0; k4 < FDIM / 4; ++k4) {
        float4 w = W4[k4];
        #pragma unroll
        for (int i = 0; i < NODE_TILE; ++i) {
            const float4 xv = reinterpret_cast<const float4*>(xs[i])[k4];
            acc[i] += xv.x * w.x + xv.y * w.y + xv.z * w.z + xv.w * w.w;
        }
    }

    float* dstp = (t < FDIM) ? (xl + node0 * FDIM + t)
                             : (xr + node0 * FDIM + (t - FDIM));
    #pragma unroll
    for (int i = 0; i < NODE_TILE; ++i) dstp[i * FDIM] = acc[i];
}

// ---------------- CSR build --------------------------------------------
__global__ void gat_zero_kernel(int* __restrict__ deg) {
    int i = blockIdx.x * blockDim.x + threadIdx.x;
    if (i < NN) deg[i] = 0;
}

__global__ void gat_hist_kernel(const int* __restrict__ ei, int* __restrict__ deg) {
    int m = blockIdx.x * blockDim.x + threadIdx.x;
    if (m < NE) atomicAdd(&deg[ei[NE + m]], 1);
}

__global__ __launch_bounds__(SCAN_BLOCK) void gat_blocksum_kernel(
        const int* __restrict__ deg, int* __restrict__ blocksum) {
    int i = blockIdx.x * SCAN_BLOCK + threadIdx.x;
    int v = (i < NN) ? deg[i] : 0;
    #pragma unroll
    for (int off = 1; off < 64; off <<= 1) v += __shfl_xor(v, off);
    __shared__ int wsum[4];
    if ((threadIdx.x & 63) == 0) wsum[threadIdx.x >> 6] = v;
    __syncthreads();
    if (threadIdx.x == 0)
        blocksum[blockIdx.x] = wsum[0] + wsum[1] + wsum[2] + wsum[3];
}

__global__ __launch_bounds__(SCAN_BLOCK) void gat_scanblk_kernel(
        const int* __restrict__ blocksum, int* __restrict__ blockoff) {
    __shared__ int buf[SCAN_BLOCK];
    int t = threadIdx.x;
    int v = (t < NBLK) ? blocksum[t] : 0;
    buf[t] = v;
    __syncthreads();
    for (int off = 1; off < SCAN_BLOCK; off <<= 1) {
        int add = (t >= off) ? buf[t - off] : 0;
        __syncthreads();
        buf[t] += add;
        __syncthreads();
    }
    if (t < NBLK) blockoff[t] = buf[t] - v;   // exclusive
}

__global__ __launch_bounds__(SCAN_BLOCK) void gat_scanfinal_kernel(
        const int* __restrict__ deg, const int* __restrict__ blockoff,
        int* __restrict__ rowstart, int* __restrict__ cursor) {
    __shared__ int buf[SCAN_BLOCK];
    int t = threadIdx.x;
    int i = blockIdx.x * SCAN_BLOCK + t;
    int v = (i < NN) ? deg[i] : 0;
    buf[t] = v;
    __syncthreads();
    for (int off = 1; off < SCAN_BLOCK; off <<= 1) {
        int add = (t >= off) ? buf[t - off] : 0;
        __syncthreads();
        buf[t] += add;
        __syncthreads();
    }
    int excl = blockoff[blockIdx.x] + buf[t] - v;
    if (i < NN) { rowstart[i] = excl; cursor[i] = excl; }
    if (i == NN - 1) rowstart[NN] = excl + v;
}

__global__ void gat_fillcsr_kernel(const int* __restrict__ ei,
                                   int* __restrict__ cursor,
                                   int* __restrict__ csr_src) {
    int m = blockIdx.x * blockDim.x + threadIdx.x;
    if (m < NE) {
        int dst = ei[NE + m];
        int pos = atomicAdd(&cursor[dst], 1);
        csr_src[pos] = ei[m];
    }
}

// ---------------- fused aggregate -----------------------------------------
// 32 threads per node; lane u owns channels 4u..4u+3 (head = u>>2).
// Per-head alpha reduced over the 4-lane group via 2 shfl_xor steps.
// Edge loop unrolled x4 with independent accumulators (4 gathers in flight).
__device__ __forceinline__ void gat_edge_step(
        const float4& xi, const float4& at, const float4& xj,
        float4& acc, float& den) {
    float4 s;
    s.x = xi.x + xj.x; s.x = (s.x > 0.0f) ? s.x : NEG_SLOPE * s.x;
    s.y = xi.y + xj.y; s.y = (s.y > 0.0f) ? s.y : NEG_SLOPE * s.y;
    s.z = xi.z + xj.z; s.z = (s.z > 0.0f) ? s.z : NEG_SLOPE * s.z;
    s.w = xi.w + xj.w; s.w = (s.w > 0.0f) ? s.w : NEG_SLOPE * s.w;
    float p = at.x * s.x + at.y * s.y + at.z * s.z + at.w * s.w;
    p += __shfl_xor(p, 1);
    p += __shfl_xor(p, 2);
    float ea = __expf(p);
    acc.x += ea * xj.x; acc.y += ea * xj.y;
    acc.z += ea * xj.z; acc.w += ea * xj.w;
    den += ea;
}

__global__ __launch_bounds__(256) void gat_aggregate_kernel(
        const float* __restrict__ xl,
        const float* __restrict__ xr,
        const float* __restrict__ att,
        const float* __restrict__ bias,
        const int* __restrict__ rowstart,
        const int* __restrict__ csr_src,
        float* __restrict__ out) {
    int node = blockIdx.x * 8 + (threadIdx.x >> 5);
    int u = threadIdx.x & 31;
    if (node >= NN) return;

    const float4 xi = *reinterpret_cast<const float4*>(xr + node * FDIM + u * 4);
    const float4 at = *reinterpret_cast<const float4*>(att + u * 4);
    const float4 bi = *reinterpret_cast<const float4*>(bias + u * 4);
    int e0 = rowstart[node];
    int e1 = rowstart[node + 1];

    float4 acc0 = {0,0,0,0}, acc1 = {0,0,0,0}, acc2 = {0,0,0,0}, acc3 = {0,0,0,0};
    float den0 = 0.0f, den1 = 0.0f, den2 = 0.0f, den3 = 0.0f;

    int e = e0;
    for (; e + 4 <= e1; e += 4) {
        int s0 = csr_src[e + 0];
        int s1 = csr_src[e + 1];
        int s2 = csr_src[e + 2];
        int s3 = csr_src[e + 3];
        float4 xj0 = *reinterpret_cast<const float4*>(xl + (size_t)s0 * FDIM + u * 4);
        float4 xj1 = *reinterpret_cast<const float4*>(xl + (size_t)s1 * FDIM + u * 4);
        float4 xj2 = *reinterpret_cast<const float4*>(xl + (size_t)s2 * FDIM + u * 4);
        float4 xj3 = *reinterpret_cast<const float4*>(xl + (size_t)s3 * FDIM + u * 4);
        gat_edge_step(xi, at, xj0, acc0, den0);
        gat_edge_step(xi, at, xj1, acc1, den1);
        gat_edge_step(xi, at, xj2, acc2, den2);
        gat_edge_step(xi, at, xj3, acc3, den3);
    }
    for (; e < e1; ++e) {
        int s0 = csr_src[e];
        float4 xj0 = *reinterpret_cast<const float4*>(xl + (size_t)s0 * FDIM + u * 4);
        gat_edge_step(xi, at, xj0, acc0, den0);
    }

    float4 acc;
    acc.x = (acc0.x + acc1.x) + (acc2.x + acc3.x);
    acc.y = (acc0.y + acc1.y) + (acc2.y + acc3.y);
    acc.z = (acc0.z + acc1.z) + (acc2.z + acc3.z);
    acc.w = (acc0.w + acc1.w) + (acc2.w + acc3.w);
    float den = (den0 + den1) + (den2 + den3);

    float inv = 1.0f / (den + 1e-16f);
    float4 o;
    o.x = acc.x * inv + bi.x;
    o.y = acc.y * inv + bi.y;
    o.z = acc.z * inv + bi.z;
    o.w = acc.w * inv + bi.w;
    *reinterpret_cast<float4*>(out + (size_t)node * FDIM + u * 4) = o;
}

extern "C" void kernel_launch(void* const* d_in, const int* in_sizes, int n_in,
                              void* d_out, int out_size, void* d_ws, size_t ws_size,
                              hipStream_t stream) {
    const float* x    = (const float*)d_in[0];
    const int*   ei   = (const int*)d_in[1];
    const float* Wl   = (const float*)d_in[2];
    const float* Wr   = (const float*)d_in[3];
    const float* att  = (const float*)d_in[4];
    const float* bias = (const float*)d_in[5];
    float* out = (float*)d_out;

    // ws layout
    float* ws = (float*)d_ws;
    float* xl = ws;                                  // NN*FDIM f32
    float* xr = xl + (size_t)NN * FDIM;              // NN*FDIM f32
    int* ibase      = (int*)(xr + (size_t)NN * FDIM);
    int* deg        = ibase;                         // NN
    int* rowstart   = deg + NN;                      // NN+1
    int* cursor     = rowstart + NN + 1;             // NN
    int* blocksum   = cursor + NN;                   // NBLK (pad 256)
    int* blockoff   = blocksum + 256;                // NBLK (pad 256)
    int* csr_src    = blockoff + 256;                // NE

    gat_zero_kernel<<<(NN + 255) / 256, 256, 0, stream>>>(deg);
    gat_hist_kernel<<<(NE + 255) / 256, 256, 0, stream>>>(ei, deg);
    gat_blocksum_kernel<<<NBLK, SCAN_BLOCK, 0, stream>>>(deg, blocksum);
    gat_scanblk_kernel<<<1, SCAN_BLOCK, 0, stream>>>(blocksum, blockoff);
    gat_scanfinal_kernel<<<NBLK, SCAN_BLOCK, 0, stream>>>(deg, blockoff, rowstart, cursor);
    gat_fillcsr_kernel<<<(NE + 255) / 256, 256, 0, stream>>>(ei, cursor, csr_src);

    gat_proj_kernel<<<NN / NODE_TILE, 256, 0, stream>>>(x, Wl, Wr, xl, xr);

    gat_aggregate_kernel<<<(NN + 7) / 8, 256, 0, stream>>>(
        xl, xr, att, bias, rowstart, csr_src, out);
}

// Round 4
// 215.048 us; speedup vs baseline: 27.8252x; 1.1893x over previous
//
#include <hip/hip_runtime.h>
#include <math.h>

// GATv2Conv forward, f32. CSR-based (no f32 output atomics).
// Proj = tiled register-blocked GEMM (BM64 x BN128 x BK32, 4x8 micro-tile).
// Aggregate: 32 threads/node (float4 per lane), edge loop unrolled x4.

#define NN 50000
#define NE 800000
#define NHEADS 8
#define CH 16
#define FDIM 128
#define NEG_SLOPE 0.2f

#define SCAN_BLOCK 256
#define NBLK ((NN + SCAN_BLOCK - 1) / SCAN_BLOCK)   // 196

// ---------------- projection GEMM: [xl|xr] = x @ [Wl|Wr]^T ---------------
#define BM 64
#define BN 128
#define BK 32
#define MTILES ((NN + BM - 1) / BM)   // 782

__global__ __launch_bounds__(256) void gat_proj_gemm(
        const float* __restrict__ x,
        const float* __restrict__ Wl,
        const float* __restrict__ Wr,
        float* __restrict__ xl,
        float* __restrict__ xr) {
    __shared__ float As[BK][BM];   // 8 KB  (k-major, transposed)
    __shared__ float Bs[BK][BN];   // 16 KB (k-major, transposed)

    const int nb = blockIdx.y;                 // 0 -> Wl/xl, 1 -> Wr/xr
    const float* __restrict__ W = nb ? Wr : Wl;
    float* __restrict__ outp    = nb ? xr : xl;
    const int node0 = blockIdx.x * BM;
    const int t  = threadIdx.x;
    const int tm = t >> 4;                     // 0..15 -> rows 4tm..4tm+3
    const int tn = t & 15;                     // 0..15 -> cols 8tn..8tn+7

    // staging assignments
    const int a_node = t >> 2;                 // 0..63
    const int a_kq   = (t & 3) * 8;            // 0,8,16,24
    const int b_n    = t >> 1;                 // 0..127
    const int b_kh   = (t & 1) * 16;           // 0,16

    int arow = node0 + a_node;
    if (arow >= NN) arow = NN - 1;             // clamp (dup loads harmless)

    float4 acc[4][2];
    #pragma unroll
    for (int i = 0; i < 4; ++i) {
        acc[i][0] = make_float4(0.f, 0.f, 0.f, 0.f);
        acc[i][1] = make_float4(0.f, 0.f, 0.f, 0.f);
    }

    for (int kc = 0; kc < FDIM; kc += BK) {
        // ---- stage A (transposed) ----
        {
            const float4* xsrc = reinterpret_cast<const float4*>(
                x + (size_t)arow * FDIM + kc + a_kq);
            float4 v0 = xsrc[0];
            float4 v1 = xsrc[1];
            As[a_kq + 0][a_node] = v0.x;
            As[a_kq + 1][a_node] = v0.y;
            As[a_kq + 2][a_node] = v0.z;
            As[a_kq + 3][a_node] = v0.w;
            As[a_kq + 4][a_node] = v1.x;
            As[a_kq + 5][a_node] = v1.y;
            As[a_kq + 6][a_node] = v1.z;
            As[a_kq + 7][a_node] = v1.w;
        }
        // ---- stage B (transposed) ----
        {
            const float4* wsrc = reinterpret_cast<const float4*>(
                W + (size_t)b_n * FDIM + kc + b_kh);
            float4 v0 = wsrc[0];
            float4 v1 = wsrc[1];
            float4 v2 = wsrc[2];
            float4 v3 = wsrc[3];
            Bs[b_kh +  0][b_n] = v0.x;
            Bs[b_kh +  1][b_n] = v0.y;
            Bs[b_kh +  2][b_n] = v0.z;
            Bs[b_kh +  3][b_n] = v0.w;
            Bs[b_kh +  4][b_n] = v1.x;
            Bs[b_kh +  5][b_n] = v1.y;
            Bs[b_kh +  6][b_n] = v1.z;
            Bs[b_kh +  7][b_n] = v1.w;
            Bs[b_kh +  8][b_n] = v2.x;
            Bs[b_kh +  9][b_n] = v2.y;
            Bs[b_kh + 10][b_n] = v2.z;
            Bs[b_kh + 11][b_n] = v2.w;
            Bs[b_kh + 12][b_n] = v3.x;
            Bs[b_kh + 13][b_n] = v3.y;
            Bs[b_kh + 14][b_n] = v3.z;
            Bs[b_kh + 15][b_n] = v3.w;
        }
        __syncthreads();

        // ---- compute 32 k-steps ----
        #pragma unroll 8
        for (int k = 0; k < BK; ++k) {
            float4 a  = *reinterpret_cast<const float4*>(&As[k][tm * 4]);
            float4 b0 = *reinterpret_cast<const float4*>(&Bs[k][tn * 8]);
            float4 b1 = *reinterpret_cast<const float4*>(&Bs[k][tn * 8 + 4]);
            float am[4] = {a.x, a.y, a.z, a.w};
            #pragma unroll
            for (int i = 0; i < 4; ++i) {
                acc[i][0].x += am[i] * b0.x;
                acc[i][0].y += am[i] * b0.y;
                acc[i][0].z += am[i] * b0.z;
                acc[i][0].w += am[i] * b0.w;
                acc[i][1].x += am[i] * b1.x;
                acc[i][1].y += am[i] * b1.y;
                acc[i][1].z += am[i] * b1.z;
                acc[i][1].w += am[i] * b1.w;
            }
        }
        __syncthreads();
    }

    #pragma unroll
    for (int i = 0; i < 4; ++i) {
        int row = node0 + tm * 4 + i;
        if (row < NN) {
            float4* dst = reinterpret_cast<float4*>(
                outp + (size_t)row * FDIM + tn * 8);
            dst[0] = acc[i][0];
            dst[1] = acc[i][1];
        }
    }
}

// ---------------- CSR build --------------------------------------------
__global__ void gat_zero_kernel(int* __restrict__ deg) {
    int i = blockIdx.x * blockDim.x + threadIdx.x;
    if (i < NN) deg[i] = 0;
}

__global__ void gat_hist_kernel(const int* __restrict__ ei, int* __restrict__ deg) {
    int m = blockIdx.x * blockDim.x + threadIdx.x;
    if (m < NE) atomicAdd(&deg[ei[NE + m]], 1);
}

__global__ __launch_bounds__(SCAN_BLOCK) void gat_blocksum_kernel(
        const int* __restrict__ deg, int* __restrict__ blocksum) {
    int i = blockIdx.x * SCAN_BLOCK + threadIdx.x;
    int v = (i < NN) ? deg[i] : 0;
    #pragma unroll
    for (int off = 1; off < 64; off <<= 1) v += __shfl_xor(v, off);
    __shared__ int wsum[4];
    if ((threadIdx.x & 63) == 0) wsum[threadIdx.x >> 6] = v;
    __syncthreads();
    if (threadIdx.x == 0)
        blocksum[blockIdx.x] = wsum[0] + wsum[1] + wsum[2] + wsum[3];
}

__global__ __launch_bounds__(SCAN_BLOCK) void gat_scanblk_kernel(
        const int* __restrict__ blocksum, int* __restrict__ blockoff) {
    __shared__ int buf[SCAN_BLOCK];
    int t = threadIdx.x;
    int v = (t < NBLK) ? blocksum[t] : 0;
    buf[t] = v;
    __syncthreads();
    for (int off = 1; off < SCAN_BLOCK; off <<= 1) {
        int add = (t >= off) ? buf[t - off] : 0;
        __syncthreads();
        buf[t] += add;
        __syncthreads();
    }
    if (t < NBLK) blockoff[t] = buf[t] - v;   // exclusive
}

__global__ __launch_bounds__(SCAN_BLOCK) void gat_scanfinal_kernel(
        const int* __restrict__ deg, const int* __restrict__ blockoff,
        int* __restrict__ rowstart, int* __restrict__ cursor) {
    __shared__ int buf[SCAN_BLOCK];
    int t = threadIdx.x;
    int i = blockIdx.x * SCAN_BLOCK + t;
    int v = (i < NN) ? deg[i] : 0;
    buf[t] = v;
    __syncthreads();
    for (int off = 1; off < SCAN_BLOCK; off <<= 1) {
        int add = (t >= off) ? buf[t - off] : 0;
        __syncthreads();
        buf[t] += add;
        __syncthreads();
    }
    int excl = blockoff[blockIdx.x] + buf[t] - v;
    if (i < NN) { rowstart[i] = excl; cursor[i] = excl; }
    if (i == NN - 1) rowstart[NN] = excl + v;
}

__global__ void gat_fillcsr_kernel(const int* __restrict__ ei,
                                   int* __restrict__ cursor,
                                   int* __restrict__ csr_src) {
    int m = blockIdx.x * blockDim.x + threadIdx.x;
    if (m < NE) {
        int dst = ei[NE + m];
        int pos = atomicAdd(&cursor[dst], 1);
        csr_src[pos] = ei[m];
    }
}

// ---------------- fused aggregate -----------------------------------------
__device__ __forceinline__ void gat_edge_step(
        const float4& xi, const float4& at, const float4& xj,
        float4& acc, float& den) {
    float4 s;
    s.x = xi.x + xj.x; s.x = (s.x > 0.0f) ? s.x : NEG_SLOPE * s.x;
    s.y = xi.y + xj.y; s.y = (s.y > 0.0f) ? s.y : NEG_SLOPE * s.y;
    s.z = xi.z + xj.z; s.z = (s.z > 0.0f) ? s.z : NEG_SLOPE * s.z;
    s.w = xi.w + xj.w; s.w = (s.w > 0.0f) ? s.w : NEG_SLOPE * s.w;
    float p = at.x * s.x + at.y * s.y + at.z * s.z + at.w * s.w;
    p += __shfl_xor(p, 1);
    p += __shfl_xor(p, 2);
    float ea = __expf(p);
    acc.x += ea * xj.x; acc.y += ea * xj.y;
    acc.z += ea * xj.z; acc.w += ea * xj.w;
    den += ea;
}

__global__ __launch_bounds__(256) void gat_aggregate_kernel(
        const float* __restrict__ xl,
        const float* __restrict__ xr,
        const float* __restrict__ att,
        const float* __restrict__ bias,
        const int* __restrict__ rowstart,
        const int* __restrict__ csr_src,
        float* __restrict__ out) {
    int node = blockIdx.x * 8 + (threadIdx.x >> 5);
    int u = threadIdx.x & 31;
    if (node >= NN) return;

    const float4 xi = *reinterpret_cast<const float4*>(xr + (size_t)node * FDIM + u * 4);
    const float4 at = *reinterpret_cast<const float4*>(att + u * 4);
    const float4 bi = *reinterpret_cast<const float4*>(bias + u * 4);
    int e0 = rowstart[node];
    int e1 = rowstart[node + 1];

    float4 acc0 = {0,0,0,0}, acc1 = {0,0,0,0}, acc2 = {0,0,0,0}, acc3 = {0,0,0,0};
    float den0 = 0.0f, den1 = 0.0f, den2 = 0.0f, den3 = 0.0f;

    int e = e0;
    for (; e + 4 <= e1; e += 4) {
        int s0 = csr_src[e + 0];
        int s1 = csr_src[e + 1];
        int s2 = csr_src[e + 2];
        int s3 = csr_src[e + 3];
        float4 xj0 = *reinterpret_cast<const float4*>(xl + (size_t)s0 * FDIM + u * 4);
        float4 xj1 = *reinterpret_cast<const float4*>(xl + (size_t)s1 * FDIM + u * 4);
        float4 xj2 = *reinterpret_cast<const float4*>(xl + (size_t)s2 * FDIM + u * 4);
        float4 xj3 = *reinterpret_cast<const float4*>(xl + (size_t)s3 * FDIM + u * 4);
        gat_edge_step(xi, at, xj0, acc0, den0);
        gat_edge_step(xi, at, xj1, acc1, den1);
        gat_edge_step(xi, at, xj2, acc2, den2);
        gat_edge_step(xi, at, xj3, acc3, den3);
    }
    for (; e < e1; ++e) {
        int s0 = csr_src[e];
        float4 xj0 = *reinterpret_cast<const float4*>(xl + (size_t)s0 * FDIM + u * 4);
        gat_edge_step(xi, at, xj0, acc0, den0);
    }

    float4 acc;
    acc.x = (acc0.x + acc1.x) + (acc2.x + acc3.x);
    acc.y = (acc0.y + acc1.y) + (acc2.y + acc3.y);
    acc.z = (acc0.z + acc1.z) + (acc2.z + acc3.z);
    acc.w = (acc0.w + acc1.w) + (acc2.w + acc3.w);
    float den = (den0 + den1) + (den2 + den3);

    float inv = 1.0f / (den + 1e-16f);
    float4 o;
    o.x = acc.x * inv + bi.x;
    o.y = acc.y * inv + bi.y;
    o.z = acc.z * inv + bi.z;
    o.w = acc.w * inv + bi.w;
    *reinterpret_cast<float4*>(out + (size_t)node * FDIM + u * 4) = o;
}

extern "C" void kernel_launch(void* const* d_in, const int* in_sizes, int n_in,
                              void* d_out, int out_size, void* d_ws, size_t ws_size,
                              hipStream_t stream) {
    const float* x    = (const float*)d_in[0];
    const int*   ei   = (const int*)d_in[1];
    const float* Wl   = (const float*)d_in[2];
    const float* Wr   = (const float*)d_in[3];
    const float* att  = (const float*)d_in[4];
    const float* bias = (const float*)d_in[5];
    float* out = (float*)d_out;

    // ws layout
    float* ws = (float*)d_ws;
    float* xl = ws;                                  // NN*FDIM f32
    float* xr = xl + (size_t)NN * FDIM;              // NN*FDIM f32
    int* ibase      = (int*)(xr + (size_t)NN * FDIM);
    int* deg        = ibase;                         // NN
    int* rowstart   = deg + NN;                      // NN+1
    int* cursor     = rowstart + NN + 1;             // NN
    int* blocksum   = cursor + NN;                   // NBLK (pad 256)
    int* blockoff   = blocksum + 256;                // NBLK (pad 256)
    int* csr_src    = blockoff + 256;                // NE

    gat_zero_kernel<<<(NN + 255) / 256, 256, 0, stream>>>(deg);
    gat_hist_kernel<<<(NE + 255) / 256, 256, 0, stream>>>(ei, deg);
    gat_blocksum_kernel<<<NBLK, SCAN_BLOCK, 0, stream>>>(deg, blocksum);
    gat_scanblk_kernel<<<1, SCAN_BLOCK, 0, stream>>>(blocksum, blockoff);
    gat_scanfinal_kernel<<<NBLK, SCAN_BLOCK, 0, stream>>>(deg, blockoff, rowstart, cursor);
    gat_fillcsr_kernel<<<(NE + 255) / 256, 256, 0, stream>>>(ei, cursor, csr_src);

    dim3 pgrid(MTILES, 2);
    gat_proj_gemm<<<pgrid, 256, 0, stream>>>(x, Wl, Wr, xl, xr);

    gat_aggregate_kernel<<<(NN + 7) / 8, 256, 0, stream>>>(
        xl, xr, att, bias, rowstart, csr_src, out);
}

// Round 5
// 201.161 us; speedup vs baseline: 29.7461x; 1.0690x over previous
//
#include <hip/hip_runtime.h>
#include <hip/hip_fp16.h>
#include <math.h>

// GATv2Conv forward. CSR-based, xl/xr stored fp16 (halves gather traffic).
// Proj = tiled register-blocked f32 GEMM (BM64 x BN128 x BK32, 4x8 micro-tile),
// fp16 output. Aggregate: 32 threads/node, 8 B/lane gathers, unroll x4.

#define NN 50000
#define NE 800000
#define NHEADS 8
#define CH 16
#define FDIM 128
#define NEG_SLOPE 0.2f

#define SCAN_BLOCK 256
#define NBLK ((NN + SCAN_BLOCK - 1) / SCAN_BLOCK)   // 196

// ---------------- projection GEMM: [xl|xr] = x @ [Wl|Wr]^T (fp16 out) ----
#define BM 64
#define BN 128
#define BK 32
#define MTILES ((NN + BM - 1) / BM)   // 782

__global__ __launch_bounds__(256) void gat_proj_gemm(
        const float* __restrict__ x,
        const float* __restrict__ Wl,
        const float* __restrict__ Wr,
        __half* __restrict__ xl,
        __half* __restrict__ xr) {
    __shared__ float As[BK][BM];   // 8 KB  (k-major, transposed)
    __shared__ float Bs[BK][BN];   // 16 KB (k-major, transposed)

    const int nb = blockIdx.y;                 // 0 -> Wl/xl, 1 -> Wr/xr
    const float* __restrict__ W = nb ? Wr : Wl;
    __half* __restrict__ outp   = nb ? xr : xl;
    const int node0 = blockIdx.x * BM;
    const int t  = threadIdx.x;
    const int tm = t >> 4;                     // 0..15 -> rows 4tm..4tm+3
    const int tn = t & 15;                     // 0..15 -> cols 8tn..8tn+7

    const int a_node = t >> 2;                 // 0..63
    const int a_kq   = (t & 3) * 8;            // 0,8,16,24
    const int b_n    = t >> 1;                 // 0..127
    const int b_kh   = (t & 1) * 16;           // 0,16

    int arow = node0 + a_node;
    if (arow >= NN) arow = NN - 1;             // clamp (dup loads harmless)

    float4 acc[4][2];
    #pragma unroll
    for (int i = 0; i < 4; ++i) {
        acc[i][0] = make_float4(0.f, 0.f, 0.f, 0.f);
        acc[i][1] = make_float4(0.f, 0.f, 0.f, 0.f);
    }

    for (int kc = 0; kc < FDIM; kc += BK) {
        {
            const float4* xsrc = reinterpret_cast<const float4*>(
                x + (size_t)arow * FDIM + kc + a_kq);
            float4 v0 = xsrc[0];
            float4 v1 = xsrc[1];
            As[a_kq + 0][a_node] = v0.x;
            As[a_kq + 1][a_node] = v0.y;
            As[a_kq + 2][a_node] = v0.z;
            As[a_kq + 3][a_node] = v0.w;
            As[a_kq + 4][a_node] = v1.x;
            As[a_kq + 5][a_node] = v1.y;
            As[a_kq + 6][a_node] = v1.z;
            As[a_kq + 7][a_node] = v1.w;
        }
        {
            const float4* wsrc = reinterpret_cast<const float4*>(
                W + (size_t)b_n * FDIM + kc + b_kh);
            float4 v0 = wsrc[0];
            float4 v1 = wsrc[1];
            float4 v2 = wsrc[2];
            float4 v3 = wsrc[3];
            Bs[b_kh +  0][b_n] = v0.x;
            Bs[b_kh +  1][b_n] = v0.y;
            Bs[b_kh +  2][b_n] = v0.z;
            Bs[b_kh +  3][b_n] = v0.w;
            Bs[b_kh +  4][b_n] = v1.x;
            Bs[b_kh +  5][b_n] = v1.y;
            Bs[b_kh +  6][b_n] = v1.z;
            Bs[b_kh +  7][b_n] = v1.w;
            Bs[b_kh +  8][b_n] = v2.x;
            Bs[b_kh +  9][b_n] = v2.y;
            Bs[b_kh + 10][b_n] = v2.z;
            Bs[b_kh + 11][b_n] = v2.w;
            Bs[b_kh + 12][b_n] = v3.x;
            Bs[b_kh + 13][b_n] = v3.y;
            Bs[b_kh + 14][b_n] = v3.z;
            Bs[b_kh + 15][b_n] = v3.w;
        }
        __syncthreads();

        #pragma unroll 8
        for (int k = 0; k < BK; ++k) {
            float4 a  = *reinterpret_cast<const float4*>(&As[k][tm * 4]);
            float4 b0 = *reinterpret_cast<const float4*>(&Bs[k][tn * 8]);
            float4 b1 = *reinterpret_cast<const float4*>(&Bs[k][tn * 8 + 4]);
            float am[4] = {a.x, a.y, a.z, a.w};
            #pragma unroll
            for (int i = 0; i < 4; ++i) {
                acc[i][0].x += am[i] * b0.x;
                acc[i][0].y += am[i] * b0.y;
                acc[i][0].z += am[i] * b0.z;
                acc[i][0].w += am[i] * b0.w;
                acc[i][1].x += am[i] * b1.x;
                acc[i][1].y += am[i] * b1.y;
                acc[i][1].z += am[i] * b1.z;
                acc[i][1].w += am[i] * b1.w;
            }
        }
        __syncthreads();
    }

    #pragma unroll
    for (int i = 0; i < 4; ++i) {
        int row = node0 + tm * 4 + i;
        if (row < NN) {
            union { uint4 u; __half2 h[4]; } pk;
            pk.h[0] = __floats2half2_rn(acc[i][0].x, acc[i][0].y);
            pk.h[1] = __floats2half2_rn(acc[i][0].z, acc[i][0].w);
            pk.h[2] = __floats2half2_rn(acc[i][1].x, acc[i][1].y);
            pk.h[3] = __floats2half2_rn(acc[i][1].z, acc[i][1].w);
            *reinterpret_cast<uint4*>(outp + (size_t)row * FDIM + tn * 8) = pk.u;
        }
    }
}

// ---------------- CSR build --------------------------------------------
__global__ void gat_zero_kernel(int* __restrict__ deg) {
    int i = blockIdx.x * blockDim.x + threadIdx.x;
    if (i < NN) deg[i] = 0;
}

__global__ void gat_hist_kernel(const int* __restrict__ ei, int* __restrict__ deg) {
    int m = blockIdx.x * blockDim.x + threadIdx.x;
    if (m < NE) atomicAdd(&deg[ei[NE + m]], 1);
}

__global__ __launch_bounds__(SCAN_BLOCK) void gat_blocksum_kernel(
        const int* __restrict__ deg, int* __restrict__ blocksum) {
    int i = blockIdx.x * SCAN_BLOCK + threadIdx.x;
    int v = (i < NN) ? deg[i] : 0;
    #pragma unroll
    for (int off = 1; off < 64; off <<= 1) v += __shfl_xor(v, off);
    __shared__ int wsum[4];
    if ((threadIdx.x & 63) == 0) wsum[threadIdx.x >> 6] = v;
    __syncthreads();
    if (threadIdx.x == 0)
        blocksum[blockIdx.x] = wsum[0] + wsum[1] + wsum[2] + wsum[3];
}

__global__ __launch_bounds__(SCAN_BLOCK) void gat_scanblk_kernel(
        const int* __restrict__ blocksum, int* __restrict__ blockoff) {
    __shared__ int buf[SCAN_BLOCK];
    int t = threadIdx.x;
    int v = (t < NBLK) ? blocksum[t] : 0;
    buf[t] = v;
    __syncthreads();
    for (int off = 1; off < SCAN_BLOCK; off <<= 1) {
        int add = (t >= off) ? buf[t - off] : 0;
        __syncthreads();
        buf[t] += add;
        __syncthreads();
    }
    if (t < NBLK) blockoff[t] = buf[t] - v;   // exclusive
}

__global__ __launch_bounds__(SCAN_BLOCK) void gat_scanfinal_kernel(
        const int* __restrict__ deg, const int* __restrict__ blockoff,
        int* __restrict__ rowstart, int* __restrict__ cursor) {
    __shared__ int buf[SCAN_BLOCK];
    int t = threadIdx.x;
    int i = blockIdx.x * SCAN_BLOCK + t;
    int v = (i < NN) ? deg[i] : 0;
    buf[t] = v;
    __syncthreads();
    for (int off = 1; off < SCAN_BLOCK; off <<= 1) {
        int add = (t >= off) ? buf[t - off] : 0;
        __syncthreads();
        buf[t] += add;
        __syncthreads();
    }
    int excl = blockoff[blockIdx.x] + buf[t] - v;
    if (i < NN) { rowstart[i] = excl; cursor[i] = excl; }
    if (i == NN - 1) rowstart[NN] = excl + v;
}

__global__ void gat_fillcsr_kernel(const int* __restrict__ ei,
                                   int* __restrict__ cursor,
                                   int* __restrict__ csr_src) {
    int m = blockIdx.x * blockDim.x + threadIdx.x;
    if (m < NE) {
        int dst = ei[NE + m];
        int pos = atomicAdd(&cursor[dst], 1);
        csr_src[pos] = ei[m];
    }
}

// ---------------- fused aggregate -----------------------------------------
// 32 threads/node; lane u owns channels 4u..4u+3 (head = u>>2).
// fp16 gathers (8 B/lane), f32 math; per-head alpha via 2 shfl_xor steps.
__device__ __forceinline__ float4 load_h4(const __half* __restrict__ p) {
    float2 raw = *reinterpret_cast<const float2*>(p);
    __half2 h01 = *reinterpret_cast<const __half2*>(&raw.x);
    __half2 h23 = *reinterpret_cast<const __half2*>(&raw.y);
    float2 f01 = __half22float2(h01);
    float2 f23 = __half22float2(h23);
    return make_float4(f01.x, f01.y, f23.x, f23.y);
}

__device__ __forceinline__ void gat_edge_step(
        const float4& xi, const float4& at, const float4& xj,
        float4& acc, float& den) {
    float4 s;
    s.x = xi.x + xj.x; s.x = (s.x > 0.0f) ? s.x : NEG_SLOPE * s.x;
    s.y = xi.y + xj.y; s.y = (s.y > 0.0f) ? s.y : NEG_SLOPE * s.y;
    s.z = xi.z + xj.z; s.z = (s.z > 0.0f) ? s.z : NEG_SLOPE * s.z;
    s.w = xi.w + xj.w; s.w = (s.w > 0.0f) ? s.w : NEG_SLOPE * s.w;
    float p = at.x * s.x + at.y * s.y + at.z * s.z + at.w * s.w;
    p += __shfl_xor(p, 1);
    p += __shfl_xor(p, 2);
    float ea = __expf(p);
    acc.x += ea * xj.x; acc.y += ea * xj.y;
    acc.z += ea * xj.z; acc.w += ea * xj.w;
    den += ea;
}

__global__ __launch_bounds__(256) void gat_aggregate_kernel(
        const __half* __restrict__ xl,
        const __half* __restrict__ xr,
        const float* __restrict__ att,
        const float* __restrict__ bias,
        const int* __restrict__ rowstart,
        const int* __restrict__ csr_src,
        float* __restrict__ out) {
    int node = blockIdx.x * 8 + (threadIdx.x >> 5);
    int u = threadIdx.x & 31;
    if (node >= NN) return;

    const float4 xi = load_h4(xr + (size_t)node * FDIM + u * 4);
    const float4 at = *reinterpret_cast<const float4*>(att + u * 4);
    const float4 bi = *reinterpret_cast<const float4*>(bias + u * 4);
    int e0 = rowstart[node];
    int e1 = rowstart[node + 1];

    float4 acc0 = {0,0,0,0}, acc1 = {0,0,0,0}, acc2 = {0,0,0,0}, acc3 = {0,0,0,0};
    float den0 = 0.0f, den1 = 0.0f, den2 = 0.0f, den3 = 0.0f;

    int e = e0;
    for (; e + 4 <= e1; e += 4) {
        int s0 = csr_src[e + 0];
        int s1 = csr_src[e + 1];
        int s2 = csr_src[e + 2];
        int s3 = csr_src[e + 3];
        float4 xj0 = load_h4(xl + (size_t)s0 * FDIM + u * 4);
        float4 xj1 = load_h4(xl + (size_t)s1 * FDIM + u * 4);
        float4 xj2 = load_h4(xl + (size_t)s2 * FDIM + u * 4);
        float4 xj3 = load_h4(xl + (size_t)s3 * FDIM + u * 4);
        gat_edge_step(xi, at, xj0, acc0, den0);
        gat_edge_step(xi, at, xj1, acc1, den1);
        gat_edge_step(xi, at, xj2, acc2, den2);
        gat_edge_step(xi, at, xj3, acc3, den3);
    }
    for (; e < e1; ++e) {
        int s0 = csr_src[e];
        float4 xj0 = load_h4(xl + (size_t)s0 * FDIM + u * 4);
        gat_edge_step(xi, at, xj0, acc0, den0);
    }

    float4 acc;
    acc.x = (acc0.x + acc1.x) + (acc2.x + acc3.x);
    acc.y = (acc0.y + acc1.y) + (acc2.y + acc3.y);
    acc.z = (acc0.z + acc1.z) + (acc2.z + acc3.z);
    acc.w = (acc0.w + acc1.w) + (acc2.w + acc3.w);
    float den = (den0 + den1) + (den2 + den3);

    float inv = 1.0f / (den + 1e-16f);
    float4 o;
    o.x = acc.x * inv + bi.x;
    o.y = acc.y * inv + bi.y;
    o.z = acc.z * inv + bi.z;
    o.w = acc.w * inv + bi.w;
    *reinterpret_cast<float4*>(out + (size_t)node * FDIM + u * 4) = o;
}

extern "C" void kernel_launch(void* const* d_in, const int* in_sizes, int n_in,
                              void* d_out, int out_size, void* d_ws, size_t ws_size,
                              hipStream_t stream) {
    const float* x    = (const float*)d_in[0];
    const int*   ei   = (const int*)d_in[1];
    const float* Wl   = (const float*)d_in[2];
    const float* Wr   = (const float*)d_in[3];
    const float* att  = (const float*)d_in[4];
    const float* bias = (const float*)d_in[5];
    float* out = (float*)d_out;

    // ws layout
    __half* xl = (__half*)d_ws;                      // NN*FDIM fp16
    __half* xr = xl + (size_t)NN * FDIM;             // NN*FDIM fp16
    int* ibase      = (int*)(xr + (size_t)NN * FDIM);
    int* deg        = ibase;                         // NN
    int* rowstart   = deg + NN;                      // NN+1
    int* cursor     = rowstart + NN + 1;             // NN
    int* blocksum   = cursor + NN;                   // NBLK (pad 256)
    int* blockoff   = blocksum + 256;                // NBLK (pad 256)
    int* csr_src    = blockoff + 256;                // NE

    gat_zero_kernel<<<(NN + 255) / 256, 256, 0, stream>>>(deg);
    gat_hist_kernel<<<(NE + 255) / 256, 256, 0, stream>>>(ei, deg);
    gat_blocksum_kernel<<<NBLK, SCAN_BLOCK, 0, stream>>>(deg, blocksum);
    gat_scanblk_kernel<<<1, SCAN_BLOCK, 0, stream>>>(blocksum, blockoff);
    gat_scanfinal_kernel<<<NBLK, SCAN_BLOCK, 0, stream>>>(deg, blockoff, rowstart, cursor);
    gat_fillcsr_kernel<<<(NE + 255) / 256, 256, 0, stream>>>(ei, cursor, csr_src);

    dim3 pgrid(MTILES, 2);
    gat_proj_gemm<<<pgrid, 256, 0, stream>>>(x, Wl, Wr, xl, xr);

    gat_aggregate_kernel<<<(NN + 7) / 8, 256, 0, stream>>>(
        xl, xr, att, bias, rowstart, csr_src, out);
}

// Round 6
// 200.243 us; speedup vs baseline: 29.8825x; 1.0046x over previous
//
#include <hip/hip_runtime.h>
#include <hip/hip_fp16.h>
#include <math.h>

// GATv2Conv forward. CSR-based, xl/xr stored fp16.
// Proj GEMM: BM64 x BN128 x BK32, 4x8 micro-tile, bank-conflict-free LDS
// (row-major padded As, group-swizzled Bs). Aggregate: 32 thr/node fp16 gathers.

#define NN 50000
#define NE 800000
#define NHEADS 8
#define CH 16
#define FDIM 128
#define NEG_SLOPE 0.2f

#define SCAN_BLOCK 256
#define NBLK ((NN + SCAN_BLOCK - 1) / SCAN_BLOCK)   // 196

// ---------------- projection GEMM: [xl|xr] = x @ [Wl|Wr]^T (fp16 out) ----
#define BM 64
#define BN 128
#define BK 32
#define AS_LD (BK + 4)     // 36 floats
#define BS_LD 144          // swizzled row stride
#define MTILES ((NN + BM - 1) / BM)   // 782

// column-group swizzle: group g (8 floats) starts at 8g + 4*(g>>2)
__device__ __forceinline__ int bs_swz(int g) { return g * 8 + (g >> 2) * 4; }

__global__ __launch_bounds__(256) void gat_proj_gemm(
        const float* __restrict__ x,
        const float* __restrict__ Wl,
        const float* __restrict__ Wr,
        __half* __restrict__ xl,
        __half* __restrict__ xr) {
    __shared__ float As[BM][AS_LD];   // 9.2 KB, row-major padded
    __shared__ float Bs[BK][BS_LD];   // 18.4 KB, k-major, group-swizzled cols

    const int nb = blockIdx.y;                 // 0 -> Wl/xl, 1 -> Wr/xr
    const float* __restrict__ W = nb ? Wr : Wl;
    __half* __restrict__ outp   = nb ? xr : xl;
    const int node0 = blockIdx.x * BM;
    const int t  = threadIdx.x;
    const int tm = t >> 4;                     // 0..15 -> rows 4tm..4tm+3
    const int tn = t & 15;                     // 0..15 -> cols 8tn..8tn+7
    const int sB = bs_swz(tn);

    const int a_node = t >> 2;                 // 0..63
    const int a_kq   = (t & 3) * 8;            // 0,8,16,24
    const int b_n    = t >> 1;                 // 0..127
    const int b_kh   = (t & 1) * 16;           // 0,16
    const int b_col  = bs_swz(b_n >> 3) + (b_n & 7);

    int arow = node0 + a_node;
    if (arow >= NN) arow = NN - 1;             // clamp (dup loads harmless)

    float4 acc[4][2];
    #pragma unroll
    for (int i = 0; i < 4; ++i) {
        acc[i][0] = make_float4(0.f, 0.f, 0.f, 0.f);
        acc[i][1] = make_float4(0.f, 0.f, 0.f, 0.f);
    }

    for (int kc = 0; kc < FDIM; kc += BK) {
        // ---- stage A (row-major, two b128 writes) ----
        {
            const float4* xsrc = reinterpret_cast<const float4*>(
                x + (size_t)arow * FDIM + kc + a_kq);
            float4 v0 = xsrc[0];
            float4 v1 = xsrc[1];
            *reinterpret_cast<float4*>(&As[a_node][a_kq])     = v0;
            *reinterpret_cast<float4*>(&As[a_node][a_kq + 4]) = v1;
        }
        // ---- stage B (k-major, swizzled col, scalar writes 2-way max) ----
        {
            const float4* wsrc = reinterpret_cast<const float4*>(
                W + (size_t)b_n * FDIM + kc + b_kh);
            float4 v0 = wsrc[0];
            float4 v1 = wsrc[1];
            float4 v2 = wsrc[2];
            float4 v3 = wsrc[3];
            Bs[b_kh +  0][b_col] = v0.x;
            Bs[b_kh +  1][b_col] = v0.y;
            Bs[b_kh +  2][b_col] = v0.z;
            Bs[b_kh +  3][b_col] = v0.w;
            Bs[b_kh +  4][b_col] = v1.x;
            Bs[b_kh +  5][b_col] = v1.y;
            Bs[b_kh +  6][b_col] = v1.z;
            Bs[b_kh +  7][b_col] = v1.w;
            Bs[b_kh +  8][b_col] = v2.x;
            Bs[b_kh +  9][b_col] = v2.y;
            Bs[b_kh + 10][b_col] = v2.z;
            Bs[b_kh + 11][b_col] = v2.w;
            Bs[b_kh + 12][b_col] = v3.x;
            Bs[b_kh + 13][b_col] = v3.y;
            Bs[b_kh + 14][b_col] = v3.z;
            Bs[b_kh + 15][b_col] = v3.w;
        }
        __syncthreads();

        // ---- compute, k in chunks of 4 ----
        #pragma unroll
        for (int k0 = 0; k0 < BK; k0 += 4) {
            float4 af[4];
            #pragma unroll
            for (int i = 0; i < 4; ++i)
                af[i] = *reinterpret_cast<const float4*>(&As[tm * 4 + i][k0]);
            #pragma unroll
            for (int kk = 0; kk < 4; ++kk) {
                float4 b0 = *reinterpret_cast<const float4*>(&Bs[k0 + kk][sB]);
                float4 b1 = *reinterpret_cast<const float4*>(&Bs[k0 + kk][sB + 4]);
                float am[4];
                am[0] = (&af[0].x)[kk];
                am[1] = (&af[1].x)[kk];
                am[2] = (&af[2].x)[kk];
                am[3] = (&af[3].x)[kk];
                #pragma unroll
                for (int i = 0; i < 4; ++i) {
                    acc[i][0].x += am[i] * b0.x;
                    acc[i][0].y += am[i] * b0.y;
                    acc[i][0].z += am[i] * b0.z;
                    acc[i][0].w += am[i] * b0.w;
                    acc[i][1].x += am[i] * b1.x;
                    acc[i][1].y += am[i] * b1.y;
                    acc[i][1].z += am[i] * b1.z;
                    acc[i][1].w += am[i] * b1.w;
                }
            }
        }
        __syncthreads();
    }

    #pragma unroll
    for (int i = 0; i < 4; ++i) {
        int row = node0 + tm * 4 + i;
        if (row < NN) {
            union { uint4 u; __half2 h[4]; } pk;
            pk.h[0] = __floats2half2_rn(acc[i][0].x, acc[i][0].y);
            pk.h[1] = __floats2half2_rn(acc[i][0].z, acc[i][0].w);
            pk.h[2] = __floats2half2_rn(acc[i][1].x, acc[i][1].y);
            pk.h[3] = __floats2half2_rn(acc[i][1].z, acc[i][1].w);
            *reinterpret_cast<uint4*>(outp + (size_t)row * FDIM + tn * 8) = pk.u;
        }
    }
}

// ---------------- CSR build --------------------------------------------
__global__ void gat_zero_kernel(int* __restrict__ deg) {
    int i = blockIdx.x * blockDim.x + threadIdx.x;
    if (i < NN) deg[i] = 0;
}

__global__ void gat_hist_kernel(const int* __restrict__ ei, int* __restrict__ deg) {
    int m = blockIdx.x * blockDim.x + threadIdx.x;
    if (m < NE) atomicAdd(&deg[ei[NE + m]], 1);
}

__global__ __launch_bounds__(SCAN_BLOCK) void gat_blocksum_kernel(
        const int* __restrict__ deg, int* __restrict__ blocksum) {
    int i = blockIdx.x * SCAN_BLOCK + threadIdx.x;
    int v = (i < NN) ? deg[i] : 0;
    #pragma unroll
    for (int off = 1; off < 64; off <<= 1) v += __shfl_xor(v, off);
    __shared__ int wsum[4];
    if ((threadIdx.x & 63) == 0) wsum[threadIdx.x >> 6] = v;
    __syncthreads();
    if (threadIdx.x == 0)
        blocksum[blockIdx.x] = wsum[0] + wsum[1] + wsum[2] + wsum[3];
}

__global__ __launch_bounds__(SCAN_BLOCK) void gat_scanblk_kernel(
        const int* __restrict__ blocksum, int* __restrict__ blockoff) {
    __shared__ int buf[SCAN_BLOCK];
    int t = threadIdx.x;
    int v = (t < NBLK) ? blocksum[t] : 0;
    buf[t] = v;
    __syncthreads();
    for (int off = 1; off < SCAN_BLOCK; off <<= 1) {
        int add = (t >= off) ? buf[t - off] : 0;
        __syncthreads();
        buf[t] += add;
        __syncthreads();
    }
    if (t < NBLK) blockoff[t] = buf[t] - v;   // exclusive
}

__global__ __launch_bounds__(SCAN_BLOCK) void gat_scanfinal_kernel(
        const int* __restrict__ deg, const int* __restrict__ blockoff,
        int* __restrict__ rowstart, int* __restrict__ cursor) {
    __shared__ int buf[SCAN_BLOCK];
    int t = threadIdx.x;
    int i = blockIdx.x * SCAN_BLOCK + t;
    int v = (i < NN) ? deg[i] : 0;
    buf[t] = v;
    __syncthreads();
    for (int off = 1; off < SCAN_BLOCK; off <<= 1) {
        int add = (t >= off) ? buf[t - off] : 0;
        __syncthreads();
        buf[t] += add;
        __syncthreads();
    }
    int excl = blockoff[blockIdx.x] + buf[t] - v;
    if (i < NN) { rowstart[i] = excl; cursor[i] = excl; }
    if (i == NN - 1) rowstart[NN] = excl + v;
}

__global__ void gat_fillcsr_kernel(const int* __restrict__ ei,
                                   int* __restrict__ cursor,
                                   int* __restrict__ csr_src) {
    int m = blockIdx.x * blockDim.x + threadIdx.x;
    if (m < NE) {
        int dst = ei[NE + m];
        int pos = atomicAdd(&cursor[dst], 1);
        csr_src[pos] = ei[m];
    }
}

// ---------------- fused aggregate -----------------------------------------
__device__ __forceinline__ float4 load_h4(const __half* __restrict__ p) {
    float2 raw = *reinterpret_cast<const float2*>(p);
    __half2 h01 = *reinterpret_cast<const __half2*>(&raw.x);
    __half2 h23 = *reinterpret_cast<const __half2*>(&raw.y);
    float2 f01 = __half22float2(h01);
    float2 f23 = __half22float2(h23);
    return make_float4(f01.x, f01.y, f23.x, f23.y);
}

__device__ __forceinline__ void gat_edge_step(
        const float4& xi, const float4& at, const float4& xj,
        float4& acc, float& den) {
    float4 s;
    s.x = xi.x + xj.x; s.x = (s.x > 0.0f) ? s.x : NEG_SLOPE * s.x;
    s.y = xi.y + xj.y; s.y = (s.y > 0.0f) ? s.y : NEG_SLOPE * s.y;
    s.z = xi.z + xj.z; s.z = (s.z > 0.0f) ? s.z : NEG_SLOPE * s.z;
    s.w = xi.w + xj.w; s.w = (s.w > 0.0f) ? s.w : NEG_SLOPE * s.w;
    float p = at.x * s.x + at.y * s.y + at.z * s.z + at.w * s.w;
    p += __shfl_xor(p, 1);
    p += __shfl_xor(p, 2);
    float ea = __expf(p);
    acc.x += ea * xj.x; acc.y += ea * xj.y;
    acc.z += ea * xj.z; acc.w += ea * xj.w;
    den += ea;
}

__global__ __launch_bounds__(256) void gat_aggregate_kernel(
        const __half* __restrict__ xl,
        const __half* __restrict__ xr,
        const float* __restrict__ att,
        const float* __restrict__ bias,
        const int* __restrict__ rowstart,
        const int* __restrict__ csr_src,
        float* __restrict__ out) {
    int node = blockIdx.x * 8 + (threadIdx.x >> 5);
    int u = threadIdx.x & 31;
    if (node >= NN) return;

    const float4 xi = load_h4(xr + (size_t)node * FDIM + u * 4);
    const float4 at = *reinterpret_cast<const float4*>(att + u * 4);
    const float4 bi = *reinterpret_cast<const float4*>(bias + u * 4);
    int e0 = rowstart[node];
    int e1 = rowstart[node + 1];

    float4 acc0 = {0,0,0,0}, acc1 = {0,0,0,0}, acc2 = {0,0,0,0}, acc3 = {0,0,0,0};
    float den0 = 0.0f, den1 = 0.0f, den2 = 0.0f, den3 = 0.0f;

    int e = e0;
    for (; e + 4 <= e1; e += 4) {
        int s0 = csr_src[e + 0];
        int s1 = csr_src[e + 1];
        int s2 = csr_src[e + 2];
        int s3 = csr_src[e + 3];
        float4 xj0 = load_h4(xl + (size_t)s0 * FDIM + u * 4);
        float4 xj1 = load_h4(xl + (size_t)s1 * FDIM + u * 4);
        float4 xj2 = load_h4(xl + (size_t)s2 * FDIM + u * 4);
        float4 xj3 = load_h4(xl + (size_t)s3 * FDIM + u * 4);
        gat_edge_step(xi, at, xj0, acc0, den0);
        gat_edge_step(xi, at, xj1, acc1, den1);
        gat_edge_step(xi, at, xj2, acc2, den2);
        gat_edge_step(xi, at, xj3, acc3, den3);
    }
    for (; e < e1; ++e) {
        int s0 = csr_src[e];
        float4 xj0 = load_h4(xl + (size_t)s0 * FDIM + u * 4);
        gat_edge_step(xi, at, xj0, acc0, den0);
    }

    float4 acc;
    acc.x = (acc0.x + acc1.x) + (acc2.x + acc3.x);
    acc.y = (acc0.y + acc1.y) + (acc2.y + acc3.y);
    acc.z = (acc0.z + acc1.z) + (acc2.z + acc3.z);
    acc.w = (acc0.w + acc1.w) + (acc2.w + acc3.w);
    float den = (den0 + den1) + (den2 + den3);

    float inv = 1.0f / (den + 1e-16f);
    float4 o;
    o.x = acc.x * inv + bi.x;
    o.y = acc.y * inv + bi.y;
    o.z = acc.z * inv + bi.z;
    o.w = acc.w * inv + bi.w;
    *reinterpret_cast<float4*>(out + (size_t)node * FDIM + u * 4) = o;
}

extern "C" void kernel_launch(void* const* d_in, const int* in_sizes, int n_in,
                              void* d_out, int out_size, void* d_ws, size_t ws_size,
                              hipStream_t stream) {
    const float* x    = (const float*)d_in[0];
    const int*   ei   = (const int*)d_in[1];
    const float* Wl   = (const float*)d_in[2];
    const float* Wr   = (const float*)d_in[3];
    const float* att  = (const float*)d_in[4];
    const float* bias = (const float*)d_in[5];
    float* out = (float*)d_out;

    // ws layout
    __half* xl = (__half*)d_ws;                      // NN*FDIM fp16
    __half* xr = xl + (size_t)NN * FDIM;             // NN*FDIM fp16
    int* ibase      = (int*)(xr + (size_t)NN * FDIM);
    int* deg        = ibase;                         // NN
    int* rowstart   = deg + NN;                      // NN+1
    int* cursor     = rowstart + NN + 1;             // NN
    int* blocksum   = cursor + NN;                   // NBLK (pad 256)
    int* blockoff   = blocksum + 256;                // NBLK (pad 256)
    int* csr_src    = blockoff + 256;                // NE

    gat_zero_kernel<<<(NN + 255) / 256, 256, 0, stream>>>(deg);
    gat_hist_kernel<<<(NE + 255) / 256, 256, 0, stream>>>(ei, deg);
    gat_blocksum_kernel<<<NBLK, SCAN_BLOCK, 0, stream>>>(deg, blocksum);
    gat_scanblk_kernel<<<1, SCAN_BLOCK, 0, stream>>>(blocksum, blockoff);
    gat_scanfinal_kernel<<<NBLK, SCAN_BLOCK, 0, stream>>>(deg, blockoff, rowstart, cursor);
    gat_fillcsr_kernel<<<(NE + 255) / 256, 256, 0, stream>>>(ei, cursor, csr_src);

    dim3 pgrid(MTILES, 2);
    gat_proj_gemm<<<pgrid, 256, 0, stream>>>(x, Wl, Wr, xl, xr);

    gat_aggregate_kernel<<<(NN + 7) / 8, 256, 0, stream>>>(
        xl, xr, att, bias, rowstart, csr_src, out);
}

// Round 7
// 140.508 us; speedup vs baseline: 42.5866x; 1.4251x over previous
//
#include <hip/hip_runtime.h>
#include <hip/hip_fp16.h>
#include <math.h>

// GATv2Conv forward. fp16 xl/xr; CSR built via hierarchical LDS binning
// (dense writes, no scattered-line HBM writeback).
// Proj GEMM: BM64 x BN128 x BK32, swizzled LDS. Aggregate: 32 thr/node.

#define NN 50000
#define NE 800000
#define NHEADS 8
#define CH 16
#define FDIM 128
#define NEG_SLOPE 0.2f

#define BSHIFT 8
#define NBUCK ((NN + 255) >> 8)          // 196 coarse buckets (dst>>8)
#define CHUNK 4096
#define NCHUNK ((NE + CHUNK - 1) / CHUNK) // 196

// ---------------- projection GEMM: [xl|xr] = x @ [Wl|Wr]^T (fp16 out) ----
#define BM 64
#define BN 128
#define BK 32
#define AS_LD (BK + 4)
#define BS_LD 144
#define MTILES ((NN + BM - 1) / BM)   // 782

__device__ __forceinline__ int bs_swz(int g) { return g * 8 + (g >> 2) * 4; }

__global__ __launch_bounds__(256) void gat_proj_gemm(
        const float* __restrict__ x,
        const float* __restrict__ Wl,
        const float* __restrict__ Wr,
        __half* __restrict__ xl,
        __half* __restrict__ xr) {
    __shared__ float As[BM][AS_LD];
    __shared__ float Bs[BK][BS_LD];

    const int nb = blockIdx.y;
    const float* __restrict__ W = nb ? Wr : Wl;
    __half* __restrict__ outp   = nb ? xr : xl;
    const int node0 = blockIdx.x * BM;
    const int t  = threadIdx.x;
    const int tm = t >> 4;
    const int tn = t & 15;
    const int sB = bs_swz(tn);

    const int a_node = t >> 2;
    const int a_kq   = (t & 3) * 8;
    const int b_n    = t >> 1;
    const int b_kh   = (t & 1) * 16;
    const int b_col  = bs_swz(b_n >> 3) + (b_n & 7);

    int arow = node0 + a_node;
    if (arow >= NN) arow = NN - 1;

    float4 acc[4][2];
    #pragma unroll
    for (int i = 0; i < 4; ++i) {
        acc[i][0] = make_float4(0.f, 0.f, 0.f, 0.f);
        acc[i][1] = make_float4(0.f, 0.f, 0.f, 0.f);
    }

    for (int kc = 0; kc < FDIM; kc += BK) {
        {
            const float4* xsrc = reinterpret_cast<const float4*>(
                x + (size_t)arow * FDIM + kc + a_kq);
            float4 v0 = xsrc[0];
            float4 v1 = xsrc[1];
            *reinterpret_cast<float4*>(&As[a_node][a_kq])     = v0;
            *reinterpret_cast<float4*>(&As[a_node][a_kq + 4]) = v1;
        }
        {
            const float4* wsrc = reinterpret_cast<const float4*>(
                W + (size_t)b_n * FDIM + kc + b_kh);
            float4 v0 = wsrc[0];
            float4 v1 = wsrc[1];
            float4 v2 = wsrc[2];
            float4 v3 = wsrc[3];
            Bs[b_kh +  0][b_col] = v0.x;
            Bs[b_kh +  1][b_col] = v0.y;
            Bs[b_kh +  2][b_col] = v0.z;
            Bs[b_kh +  3][b_col] = v0.w;
            Bs[b_kh +  4][b_col] = v1.x;
            Bs[b_kh +  5][b_col] = v1.y;
            Bs[b_kh +  6][b_col] = v1.z;
            Bs[b_kh +  7][b_col] = v1.w;
            Bs[b_kh +  8][b_col] = v2.x;
            Bs[b_kh +  9][b_col] = v2.y;
            Bs[b_kh + 10][b_col] = v2.z;
            Bs[b_kh + 11][b_col] = v2.w;
            Bs[b_kh + 12][b_col] = v3.x;
            Bs[b_kh + 13][b_col] = v3.y;
            Bs[b_kh + 14][b_col] = v3.z;
            Bs[b_kh + 15][b_col] = v3.w;
        }
        __syncthreads();

        #pragma unroll
        for (int k0 = 0; k0 < BK; k0 += 4) {
            float4 af[4];
            #pragma unroll
            for (int i = 0; i < 4; ++i)
                af[i] = *reinterpret_cast<const float4*>(&As[tm * 4 + i][k0]);
            #pragma unroll
            for (int kk = 0; kk < 4; ++kk) {
                float4 b0 = *reinterpret_cast<const float4*>(&Bs[k0 + kk][sB]);
                float4 b1 = *reinterpret_cast<const float4*>(&Bs[k0 + kk][sB + 4]);
                float am[4];
                am[0] = (&af[0].x)[kk];
                am[1] = (&af[1].x)[kk];
                am[2] = (&af[2].x)[kk];
                am[3] = (&af[3].x)[kk];
                #pragma unroll
                for (int i = 0; i < 4; ++i) {
                    acc[i][0].x += am[i] * b0.x;
                    acc[i][0].y += am[i] * b0.y;
                    acc[i][0].z += am[i] * b0.z;
                    acc[i][0].w += am[i] * b0.w;
                    acc[i][1].x += am[i] * b1.x;
                    acc[i][1].y += am[i] * b1.y;
                    acc[i][1].z += am[i] * b1.z;
                    acc[i][1].w += am[i] * b1.w;
                }
            }
        }
        __syncthreads();
    }

    #pragma unroll
    for (int i = 0; i < 4; ++i) {
        int row = node0 + tm * 4 + i;
        if (row < NN) {
            union { uint4 u; __half2 h[4]; } pk;
            pk.h[0] = __floats2half2_rn(acc[i][0].x, acc[i][0].y);
            pk.h[1] = __floats2half2_rn(acc[i][0].z, acc[i][0].w);
            pk.h[2] = __floats2half2_rn(acc[i][1].x, acc[i][1].y);
            pk.h[3] = __floats2half2_rn(acc[i][1].z, acc[i][1].w);
            *reinterpret_cast<uint4*>(outp + (size_t)row * FDIM + tn * 8) = pk.u;
        }
    }
}

// ---------------- CSR build via hierarchical binning ---------------------
__global__ void gat_zero_cnt(int* __restrict__ bcnt) {
    int t = threadIdx.x;
    if (t < NBUCK) bcnt[t] = 0;
}

// coarse histogram, LDS-aggregated
__global__ __launch_bounds__(256) void gat_bucket_count(
        const int* __restrict__ ei, int* __restrict__ bcnt) {
    __shared__ int hist[NBUCK];
    int t = threadIdx.x;
    for (int i = t; i < NBUCK; i += 256) hist[i] = 0;
    __syncthreads();
    int base = blockIdx.x * CHUNK;
    #pragma unroll
    for (int i = 0; i < CHUNK / 256; ++i) {
        int m = base + i * 256 + t;
        if (m < NE) atomicAdd(&hist[ei[NE + m] >> BSHIFT], 1);
    }
    __syncthreads();
    for (int i = t; i < NBUCK; i += 256)
        if (hist[i]) atomicAdd(&bcnt[i], hist[i]);
}

// scan 196 bucket counts -> base + cursor; rowstart[NN] = NE
__global__ __launch_bounds__(256) void gat_bucket_scan(
        const int* __restrict__ bcnt,
        int* __restrict__ bbase,
        int* __restrict__ bcursor,
        int* __restrict__ rowstart) {
    __shared__ int buf[256];
    int t = threadIdx.x;
    int v = (t < NBUCK) ? bcnt[t] : 0;
    buf[t] = v;
    __syncthreads();
    for (int off = 1; off < 256; off <<= 1) {
        int add = (t >= off) ? buf[t - off] : 0;
        __syncthreads();
        buf[t] += add;
        __syncthreads();
    }
    if (t < NBUCK) {
        int excl = buf[t] - v;
        bbase[t]   = excl;
        bcursor[t] = excl;
    }
    if (t == 0) {
        bbase[NBUCK] = NE;
        rowstart[NN] = NE;
    }
}

// bin edges into coarse buckets; packed (src, dst&255); dense writes
__global__ __launch_bounds__(256) void gat_bin_pass(
        const int* __restrict__ ei,
        int* __restrict__ bcursor,
        int2* __restrict__ binned) {
    __shared__ int hist[NBUCK];
    __shared__ int base_l[NBUCK];
    int t = threadIdx.x;
    for (int i = t; i < NBUCK; i += 256) hist[i] = 0;
    __syncthreads();

    int cbase = blockIdx.x * CHUNK;
    int s[CHUNK / 256], d[CHUNK / 256], r[CHUNK / 256];
    #pragma unroll
    for (int i = 0; i < CHUNK / 256; ++i) {
        int m = cbase + i * 256 + t;
        if (m < NE) {
            s[i] = ei[m];
            d[i] = ei[NE + m];
            r[i] = atomicAdd(&hist[d[i] >> BSHIFT], 1);
        } else {
            d[i] = -1;
        }
    }
    __syncthreads();
    for (int i = t; i < NBUCK; i += 256)
        base_l[i] = hist[i] ? atomicAdd(&bcursor[i], hist[i]) : 0;
    __syncthreads();
    #pragma unroll
    for (int i = 0; i < CHUNK / 256; ++i) {
        if (d[i] >= 0) {
            int pos = base_l[d[i] >> BSHIFT] + r[i];
            binned[pos] = make_int2(s[i], d[i] & 255);
        }
    }
}

// per-bucket fine sort: count 256 fine nodes, scan, write rowstart,
// scatter csr_src within the block's private compact region.
__global__ __launch_bounds__(256) void gat_fine_pass(
        const int2* __restrict__ binned,
        const int* __restrict__ bbase,
        int* __restrict__ rowstart,
        int* __restrict__ csr_src) {
    __shared__ int cnt_c[256];
    __shared__ int sbuf[256];
    __shared__ int cur_c[256];
    int t = threadIdx.x;
    int b = blockIdx.x;
    int base = bbase[b];
    int cnt  = bbase[b + 1] - base;

    cnt_c[t] = 0;
    __syncthreads();
    for (int j = t; j < cnt; j += 256)
        atomicAdd(&cnt_c[binned[base + j].y], 1);
    __syncthreads();

    int v = cnt_c[t];
    sbuf[t] = v;
    __syncthreads();
    for (int off = 1; off < 256; off <<= 1) {
        int add = (t >= off) ? sbuf[t - off] : 0;
        __syncthreads();
        sbuf[t] += add;
        __syncthreads();
    }
    int excl = sbuf[t] - v;
    cur_c[t] = excl;
    int node = (b << BSHIFT) + t;
    if (node < NN) rowstart[node] = base + excl;
    __syncthreads();

    for (int j = t; j < cnt; j += 256) {
        int2 e = binned[base + j];
        int pos = atomicAdd(&cur_c[e.y], 1);
        csr_src[base + pos] = e.x;
    }
}

// ---------------- fused aggregate -----------------------------------------
__device__ __forceinline__ float4 load_h4(const __half* __restrict__ p) {
    float2 raw = *reinterpret_cast<const float2*>(p);
    __half2 h01 = *reinterpret_cast<const __half2*>(&raw.x);
    __half2 h23 = *reinterpret_cast<const __half2*>(&raw.y);
    float2 f01 = __half22float2(h01);
    float2 f23 = __half22float2(h23);
    return make_float4(f01.x, f01.y, f23.x, f23.y);
}

__device__ __forceinline__ void gat_edge_step(
        const float4& xi, const float4& at, const float4& xj,
        float4& acc, float& den) {
    float4 s;
    s.x = xi.x + xj.x; s.x = (s.x > 0.0f) ? s.x : NEG_SLOPE * s.x;
    s.y = xi.y + xj.y; s.y = (s.y > 0.0f) ? s.y : NEG_SLOPE * s.y;
    s.z = xi.z + xj.z; s.z = (s.z > 0.0f) ? s.z : NEG_SLOPE * s.z;
    s.w = xi.w + xj.w; s.w = (s.w > 0.0f) ? s.w : NEG_SLOPE * s.w;
    float p = at.x * s.x + at.y * s.y + at.z * s.z + at.w * s.w;
    p += __shfl_xor(p, 1);
    p += __shfl_xor(p, 2);
    float ea = __expf(p);
    acc.x += ea * xj.x; acc.y += ea * xj.y;
    acc.z += ea * xj.z; acc.w += ea * xj.w;
    den += ea;
}

__global__ __launch_bounds__(256) void gat_aggregate_kernel(
        const __half* __restrict__ xl,
        const __half* __restrict__ xr,
        const float* __restrict__ att,
        const float* __restrict__ bias,
        const int* __restrict__ rowstart,
        const int* __restrict__ csr_src,
        float* __restrict__ out) {
    int node = blockIdx.x * 8 + (threadIdx.x >> 5);
    int u = threadIdx.x & 31;
    if (node >= NN) return;

    const float4 xi = load_h4(xr + (size_t)node * FDIM + u * 4);
    const float4 at = *reinterpret_cast<const float4*>(att + u * 4);
    const float4 bi = *reinterpret_cast<const float4*>(bias + u * 4);
    int e0 = rowstart[node];
    int e1 = rowstart[node + 1];

    float4 acc0 = {0,0,0,0}, acc1 = {0,0,0,0}, acc2 = {0,0,0,0}, acc3 = {0,0,0,0};
    float den0 = 0.0f, den1 = 0.0f, den2 = 0.0f, den3 = 0.0f;

    int e = e0;
    for (; e + 4 <= e1; e += 4) {
        int s0 = csr_src[e + 0];
        int s1 = csr_src[e + 1];
        int s2 = csr_src[e + 2];
        int s3 = csr_src[e + 3];
        float4 xj0 = load_h4(xl + (size_t)s0 * FDIM + u * 4);
        float4 xj1 = load_h4(xl + (size_t)s1 * FDIM + u * 4);
        float4 xj2 = load_h4(xl + (size_t)s2 * FDIM + u * 4);
        float4 xj3 = load_h4(xl + (size_t)s3 * FDIM + u * 4);
        gat_edge_step(xi, at, xj0, acc0, den0);
        gat_edge_step(xi, at, xj1, acc1, den1);
        gat_edge_step(xi, at, xj2, acc2, den2);
        gat_edge_step(xi, at, xj3, acc3, den3);
    }
    for (; e < e1; ++e) {
        int s0 = csr_src[e];
        float4 xj0 = load_h4(xl + (size_t)s0 * FDIM + u * 4);
        gat_edge_step(xi, at, xj0, acc0, den0);
    }

    float4 acc;
    acc.x = (acc0.x + acc1.x) + (acc2.x + acc3.x);
    acc.y = (acc0.y + acc1.y) + (acc2.y + acc3.y);
    acc.z = (acc0.z + acc1.z) + (acc2.z + acc3.z);
    acc.w = (acc0.w + acc1.w) + (acc2.w + acc3.w);
    float den = (den0 + den1) + (den2 + den3);

    float inv = 1.0f / (den + 1e-16f);
    float4 o;
    o.x = acc.x * inv + bi.x;
    o.y = acc.y * inv + bi.y;
    o.z = acc.z * inv + bi.z;
    o.w = acc.w * inv + bi.w;
    *reinterpret_cast<float4*>(out + (size_t)node * FDIM + u * 4) = o;
}

extern "C" void kernel_launch(void* const* d_in, const int* in_sizes, int n_in,
                              void* d_out, int out_size, void* d_ws, size_t ws_size,
                              hipStream_t stream) {
    const float* x    = (const float*)d_in[0];
    const int*   ei   = (const int*)d_in[1];
    const float* Wl   = (const float*)d_in[2];
    const float* Wr   = (const float*)d_in[3];
    const float* att  = (const float*)d_in[4];
    const float* bias = (const float*)d_in[5];
    float* out = (float*)d_out;

    // ws layout (d_ws is 256-aligned)
    __half* xl = (__half*)d_ws;                      // NN*FDIM fp16 (12.8 MB)
    __half* xr = xl + (size_t)NN * FDIM;             // NN*FDIM fp16
    int2* binned   = (int2*)(xr + (size_t)NN * FDIM);// NE int2 (6.4 MB, 8B aligned)
    int* csr_src   = (int*)(binned + NE);            // NE
    int* rowstart  = csr_src + NE;                   // NN+1 (pad)
    int* bcnt      = rowstart + NN + 8;              // NBUCK (pad 256)
    int* bbase     = bcnt + 256;                     // NBUCK+1 (pad 256)
    int* bcursor   = bbase + 256;                    // NBUCK

    gat_zero_cnt<<<1, 256, 0, stream>>>(bcnt);
    gat_bucket_count<<<NCHUNK, 256, 0, stream>>>(ei, bcnt);
    gat_bucket_scan<<<1, 256, 0, stream>>>(bcnt, bbase, bcursor, rowstart);
    gat_bin_pass<<<NCHUNK, 256, 0, stream>>>(ei, bcursor, binned);
    gat_fine_pass<<<NBUCK, 256, 0, stream>>>(binned, bbase, rowstart, csr_src);

    dim3 pgrid(MTILES, 2);
    gat_proj_gemm<<<pgrid, 256, 0, stream>>>(x, Wl, Wr, xl, xr);

    gat_aggregate_kernel<<<(NN + 7) / 8, 256, 0, stream>>>(
        xl, xr, att, bias, rowstart, csr_src, out);
}

// Round 8
// 114.869 us; speedup vs baseline: 52.0920x; 1.2232x over previous
//
#include <hip/hip_runtime.h>
#include <hip/hip_fp16.h>
#include <math.h>

// GATv2Conv forward. fp16 xl/xr; CSR via hierarchical LDS binning.
// Proj: MFMA f16 GEMM (single K-pass, inline f32->f16 staging, XOR-swizzled LDS).
// Aggregate: 32 thr/node fp16 gathers, unroll x4.

#define NN 50000
#define NE 800000
#define NHEADS 8
#define CH 16
#define FDIM 128
#define NEG_SLOPE 0.2f

#define BSHIFT 8
#define NBUCK ((NN + 255) >> 8)          // 196
#define CHUNK 4096
#define NCHUNK ((NE + CHUNK - 1) / CHUNK) // 196

typedef _Float16 half8 __attribute__((ext_vector_type(8)));
typedef float f32x4 __attribute__((ext_vector_type(4)));

// ---------------- projection GEMM via MFMA -------------------------------
// C[m][n] = sum_k x[m][k] * W[n][k], W = [Wl;Wr] quadrant per blockIdx.y.
// Tile: 64 rows x 64 W-rows, K=128 in one staged pass.
#define PBM 64
#define PTILES ((NN + PBM - 1) / PBM)   // 782

__global__ __launch_bounds__(256) void gat_proj_mfma(
        const float* __restrict__ x,
        const float* __restrict__ Wl,
        const float* __restrict__ Wr,
        __half* __restrict__ xl,
        __half* __restrict__ xr) {
    __shared__ __half Al[PBM][FDIM];   // 16 KB, 16B-chunk XOR-swizzled
    __shared__ __half Bl[PBM][FDIM];   // 16 KB

    const int t    = threadIdx.x;
    const int lane = t & 63;
    const int wave = t >> 6;
    const int wm   = wave >> 1;        // 0..1 : 32-row half of A-tile
    const int wn   = wave & 1;         // 0..1 : 32-row half of B-tile
    const int lr   = lane & 15;
    const int lh   = lane >> 4;

    const int row0 = blockIdx.x * PBM;
    const int y    = blockIdx.y;               // 0..3
    const float* __restrict__ Wp = (y < 2) ? Wl : Wr;
    __half* __restrict__ outp    = (y < 2) ? xl : xr;
    const int wrow0   = (y & 1) * 64;          // W row base within Wl/Wr
    const int colbase = wrow0;                 // output col base within 128

    // ---- stage A and B tiles (f32 -> f16 convert, swizzled 16B chunks) ----
    #pragma unroll
    for (int i = 0; i < 4; ++i) {
        int c   = t + i * 256;                 // 0..1023
        int row = c >> 4;
        int c16 = c & 15;
        int sc  = c16 ^ (row & 7);
        // A
        {
            int arow = row0 + row;
            if (arow >= NN) arow = NN - 1;
            const float4* src = reinterpret_cast<const float4*>(
                x + (size_t)arow * FDIM + c16 * 8);
            float4 v0 = src[0];
            float4 v1 = src[1];
            union { uint4 u; __half2 h[4]; } pk;
            pk.h[0] = __floats2half2_rn(v0.x, v0.y);
            pk.h[1] = __floats2half2_rn(v0.z, v0.w);
            pk.h[2] = __floats2half2_rn(v1.x, v1.y);
            pk.h[3] = __floats2half2_rn(v1.z, v1.w);
            *reinterpret_cast<uint4*>(&Al[row][sc * 8]) = pk.u;
        }
        // B
        {
            const float4* src = reinterpret_cast<const float4*>(
                Wp + (size_t)(wrow0 + row) * FDIM + c16 * 8);
            float4 v0 = src[0];
            float4 v1 = src[1];
            union { uint4 u; __half2 h[4]; } pk;
            pk.h[0] = __floats2half2_rn(v0.x, v0.y);
            pk.h[1] = __floats2half2_rn(v0.z, v0.w);
            pk.h[2] = __floats2half2_rn(v1.x, v1.y);
            pk.h[3] = __floats2half2_rn(v1.z, v1.w);
            *reinterpret_cast<uint4*>(&Bl[row][sc * 8]) = pk.u;
        }
    }
    __syncthreads();

    // ---- MFMA: 2x2 fragments x 4 k-chunks ----
    f32x4 acc[2][2] = {};
    const char* Ab = reinterpret_cast<const char*>(&Al[0][0]);
    const char* Bb = reinterpret_cast<const char*>(&Bl[0][0]);

    #pragma unroll
    for (int kc = 0; kc < 4; ++kc) {
        half8 a[2], b[2];
        #pragma unroll
        for (int mi = 0; mi < 2; ++mi) {
            int row = wm * 32 + mi * 16 + lr;
            int bc  = (kc * 64 + 16 * lh) ^ ((row & 7) << 4);
            a[mi] = *reinterpret_cast<const half8*>(Ab + row * 256 + bc);
        }
        #pragma unroll
        for (int ni = 0; ni < 2; ++ni) {
            int row = wn * 32 + ni * 16 + lr;
            int bc  = (kc * 64 + 16 * lh) ^ ((row & 7) << 4);
            b[ni] = *reinterpret_cast<const half8*>(Bb + row * 256 + bc);
        }
        #pragma unroll
        for (int mi = 0; mi < 2; ++mi)
            #pragma unroll
            for (int ni = 0; ni < 2; ++ni)
                acc[mi][ni] = __builtin_amdgcn_mfma_f32_16x16x32_f16(
                    a[mi], b[ni], acc[mi][ni], 0, 0, 0);
    }

    // ---- epilogue: C[row][col] -> fp16; col=lane&15, row=4*(lane>>4)+reg ----
    #pragma unroll
    for (int mi = 0; mi < 2; ++mi) {
        #pragma unroll
        for (int ni = 0; ni < 2; ++ni) {
            int gcol = colbase + wn * 32 + ni * 16 + lr;
            #pragma unroll
            for (int r = 0; r < 4; ++r) {
                int grow = row0 + wm * 32 + mi * 16 + 4 * lh + r;
                if (grow < NN)
                    outp[(size_t)grow * FDIM + gcol] = __float2half(acc[mi][ni][r]);
            }
        }
    }
}

// ---------------- CSR build via hierarchical binning ---------------------
__global__ void gat_zero_cnt(int* __restrict__ bcnt) {
    int t = threadIdx.x;
    if (t < NBUCK) bcnt[t] = 0;
}

__global__ __launch_bounds__(256) void gat_bucket_count(
        const int* __restrict__ ei, int* __restrict__ bcnt) {
    __shared__ int hist[NBUCK];
    int t = threadIdx.x;
    for (int i = t; i < NBUCK; i += 256) hist[i] = 0;
    __syncthreads();
    int base = blockIdx.x * CHUNK;
    #pragma unroll
    for (int i = 0; i < CHUNK / 256; ++i) {
        int m = base + i * 256 + t;
        if (m < NE) atomicAdd(&hist[ei[NE + m] >> BSHIFT], 1);
    }
    __syncthreads();
    for (int i = t; i < NBUCK; i += 256)
        if (hist[i]) atomicAdd(&bcnt[i], hist[i]);
}

__global__ __launch_bounds__(256) void gat_bucket_scan(
        const int* __restrict__ bcnt,
        int* __restrict__ bbase,
        int* __restrict__ bcursor,
        int* __restrict__ rowstart) {
    __shared__ int buf[256];
    int t = threadIdx.x;
    int v = (t < NBUCK) ? bcnt[t] : 0;
    buf[t] = v;
    __syncthreads();
    for (int off = 1; off < 256; off <<= 1) {
        int add = (t >= off) ? buf[t - off] : 0;
        __syncthreads();
        buf[t] += add;
        __syncthreads();
    }
    if (t < NBUCK) {
        int excl = buf[t] - v;
        bbase[t]   = excl;
        bcursor[t] = excl;
    }
    if (t == 0) {
        bbase[NBUCK] = NE;
        rowstart[NN] = NE;
    }
}

__global__ __launch_bounds__(256) void gat_bin_pass(
        const int* __restrict__ ei,
        int* __restrict__ bcursor,
        int2* __restrict__ binned) {
    __shared__ int hist[NBUCK];
    __shared__ int base_l[NBUCK];
    int t = threadIdx.x;
    for (int i = t; i < NBUCK; i += 256) hist[i] = 0;
    __syncthreads();

    int cbase = blockIdx.x * CHUNK;
    int s[CHUNK / 256], d[CHUNK / 256], r[CHUNK / 256];
    #pragma unroll
    for (int i = 0; i < CHUNK / 256; ++i) {
        int m = cbase + i * 256 + t;
        if (m < NE) {
            s[i] = ei[m];
            d[i] = ei[NE + m];
            r[i] = atomicAdd(&hist[d[i] >> BSHIFT], 1);
        } else {
            d[i] = -1;
        }
    }
    __syncthreads();
    for (int i = t; i < NBUCK; i += 256)
        base_l[i] = hist[i] ? atomicAdd(&bcursor[i], hist[i]) : 0;
    __syncthreads();
    #pragma unroll
    for (int i = 0; i < CHUNK / 256; ++i) {
        if (d[i] >= 0) {
            int pos = base_l[d[i] >> BSHIFT] + r[i];
            binned[pos] = make_int2(s[i], d[i] & 255);
        }
    }
}

__global__ __launch_bounds__(256) void gat_fine_pass(
        const int2* __restrict__ binned,
        const int* __restrict__ bbase,
        int* __restrict__ rowstart,
        int* __restrict__ csr_src) {
    __shared__ int cnt_c[256];
    __shared__ int sbuf[256];
    __shared__ int cur_c[256];
    int t = threadIdx.x;
    int b = blockIdx.x;
    int base = bbase[b];
    int cnt  = bbase[b + 1] - base;

    cnt_c[t] = 0;
    __syncthreads();
    for (int j = t; j < cnt; j += 256)
        atomicAdd(&cnt_c[binned[base + j].y], 1);
    __syncthreads();

    int v = cnt_c[t];
    sbuf[t] = v;
    __syncthreads();
    for (int off = 1; off < 256; off <<= 1) {
        int add = (t >= off) ? sbuf[t - off] : 0;
        __syncthreads();
        sbuf[t] += add;
        __syncthreads();
    }
    int excl = sbuf[t] - v;
    cur_c[t] = excl;
    int node = (b << BSHIFT) + t;
    if (node < NN) rowstart[node] = base + excl;
    __syncthreads();

    for (int j = t; j < cnt; j += 256) {
        int2 e = binned[base + j];
        int pos = atomicAdd(&cur_c[e.y], 1);
        csr_src[base + pos] = e.x;
    }
}

// ---------------- fused aggregate -----------------------------------------
__device__ __forceinline__ float4 load_h4(const __half* __restrict__ p) {
    float2 raw = *reinterpret_cast<const float2*>(p);
    __half2 h01 = *reinterpret_cast<const __half2*>(&raw.x);
    __half2 h23 = *reinterpret_cast<const __half2*>(&raw.y);
    float2 f01 = __half22float2(h01);
    float2 f23 = __half22float2(h23);
    return make_float4(f01.x, f01.y, f23.x, f23.y);
}

__device__ __forceinline__ void gat_edge_step(
        const float4& xi, const float4& at, const float4& xj,
        float4& acc, float& den) {
    float4 s;
    s.x = xi.x + xj.x; s.x = (s.x > 0.0f) ? s.x : NEG_SLOPE * s.x;
    s.y = xi.y + xj.y; s.y = (s.y > 0.0f) ? s.y : NEG_SLOPE * s.y;
    s.z = xi.z + xj.z; s.z = (s.z > 0.0f) ? s.z : NEG_SLOPE * s.z;
    s.w = xi.w + xj.w; s.w = (s.w > 0.0f) ? s.w : NEG_SLOPE * s.w;
    float p = at.x * s.x + at.y * s.y + at.z * s.z + at.w * s.w;
    p += __shfl_xor(p, 1);
    p += __shfl_xor(p, 2);
    float ea = __expf(p);
    acc.x += ea * xj.x; acc.y += ea * xj.y;
    acc.z += ea * xj.z; acc.w += ea * xj.w;
    den += ea;
}

__global__ __launch_bounds__(256) void gat_aggregate_kernel(
        const __half* __restrict__ xl,
        const __half* __restrict__ xr,
        const float* __restrict__ att,
        const float* __restrict__ bias,
        const int* __restrict__ rowstart,
        const int* __restrict__ csr_src,
        float* __restrict__ out) {
    int node = blockIdx.x * 8 + (threadIdx.x >> 5);
    int u = threadIdx.x & 31;
    if (node >= NN) return;

    const float4 xi = load_h4(xr + (size_t)node * FDIM + u * 4);
    const float4 at = *reinterpret_cast<const float4*>(att + u * 4);
    const float4 bi = *reinterpret_cast<const float4*>(bias + u * 4);
    int e0 = rowstart[node];
    int e1 = rowstart[node + 1];

    float4 acc0 = {0,0,0,0}, acc1 = {0,0,0,0}, acc2 = {0,0,0,0}, acc3 = {0,0,0,0};
    float den0 = 0.0f, den1 = 0.0f, den2 = 0.0f, den3 = 0.0f;

    int e = e0;
    for (; e + 4 <= e1; e += 4) {
        int s0 = csr_src[e + 0];
        int s1 = csr_src[e + 1];
        int s2 = csr_src[e + 2];
        int s3 = csr_src[e + 3];
        float4 xj0 = load_h4(xl + (size_t)s0 * FDIM + u * 4);
        float4 xj1 = load_h4(xl + (size_t)s1 * FDIM + u * 4);
        float4 xj2 = load_h4(xl + (size_t)s2 * FDIM + u * 4);
        float4 xj3 = load_h4(xl + (size_t)s3 * FDIM + u * 4);
        gat_edge_step(xi, at, xj0, acc0, den0);
        gat_edge_step(xi, at, xj1, acc1, den1);
        gat_edge_step(xi, at, xj2, acc2, den2);
        gat_edge_step(xi, at, xj3, acc3, den3);
    }
    for (; e < e1; ++e) {
        int s0 = csr_src[e];
        float4 xj0 = load_h4(xl + (size_t)s0 * FDIM + u * 4);
        gat_edge_step(xi, at, xj0, acc0, den0);
    }

    float4 acc;
    acc.x = (acc0.x + acc1.x) + (acc2.x + acc3.x);
    acc.y = (acc0.y + acc1.y) + (acc2.y + acc3.y);
    acc.z = (acc0.z + acc1.z) + (acc2.z + acc3.z);
    acc.w = (acc0.w + acc1.w) + (acc2.w + acc3.w);
    float den = (den0 + den1) + (den2 + den3);

    float inv = 1.0f / (den + 1e-16f);
    float4 o;
    o.x = acc.x * inv + bi.x;
    o.y = acc.y * inv + bi.y;
    o.z = acc.z * inv + bi.z;
    o.w = acc.w * inv + bi.w;
    *reinterpret_cast<float4*>(out + (size_t)node * FDIM + u * 4) = o;
}

extern "C" void kernel_launch(void* const* d_in, const int* in_sizes, int n_in,
                              void* d_out, int out_size, void* d_ws, size_t ws_size,
                              hipStream_t stream) {
    const float* x    = (const float*)d_in[0];
    const int*   ei   = (const int*)d_in[1];
    const float* Wl   = (const float*)d_in[2];
    const float* Wr   = (const float*)d_in[3];
    const float* att  = (const float*)d_in[4];
    const float* bias = (const float*)d_in[5];
    float* out = (float*)d_out;

    // ws layout (d_ws is 256-aligned)
    __half* xl = (__half*)d_ws;                      // NN*FDIM fp16
    __half* xr = xl + (size_t)NN * FDIM;             // NN*FDIM fp16
    int2* binned   = (int2*)(xr + (size_t)NN * FDIM);// NE int2
    int* csr_src   = (int*)(binned + NE);            // NE
    int* rowstart  = csr_src + NE;                   // NN+1 (pad)
    int* bcnt      = rowstart + NN + 8;              // NBUCK (pad 256)
    int* bbase     = bcnt + 256;                     // NBUCK+1 (pad 256)
    int* bcursor   = bbase + 256;                    // NBUCK

    gat_zero_cnt<<<1, 256, 0, stream>>>(bcnt);
    gat_bucket_count<<<NCHUNK, 256, 0, stream>>>(ei, bcnt);
    gat_bucket_scan<<<1, 256, 0, stream>>>(bcnt, bbase, bcursor, rowstart);
    gat_bin_pass<<<NCHUNK, 256, 0, stream>>>(ei, bcursor, binned);
    gat_fine_pass<<<NBUCK, 256, 0, stream>>>(binned, bbase, rowstart, csr_src);

    dim3 pgrid(PTILES, 4);
    gat_proj_mfma<<<pgrid, 256, 0, stream>>>(x, Wl, Wr, xl, xr);

    gat_aggregate_kernel<<<(NN + 7) / 8, 256, 0, stream>>>(
        xl, xr, att, bias, rowstart, csr_src, out);
}